// Round 3
// baseline (729.458 us; speedup 1.0000x reference)
//
#include <hip/hip_runtime.h>

constexpr int FIN = 256;   // input features
constexpr int C1  = 256;   // H1*hidden (layer-1 concat width)
constexpr int HID = 64;
constexpr int H1N = 4;
constexpr int NC  = 40;    // classes

// ---------------- edge dtype detect: int32 vs int64 -----------------------
// Samples 64 odd int32 words within the first 2E words (safe under both
// dtypes). int64 data (values < 2^31) has all-zero high halves -> stride 2.
__global__ __launch_bounds__(64)
void detect_kernel(const int* __restrict__ ei, int* __restrict__ flag, int E)
{
    int lane = threadIdx.x;                 // 64 lanes
    int q = lane * (E / 64);
    int v = ei[2 * q + 1];
    unsigned long long nz = __ballot(v != 0);
    if (lane == 0) flag[0] = (nz == 0ull) ? 2 : 1;
}

// ---------------- init: counts=1 (self loop), fill=0, BN accumulators=0 ----
__global__ __launch_bounds__(256)
void init_kernel(int* __restrict__ counts, int* __restrict__ fill,
                 float* __restrict__ colsum, float* __restrict__ colsq, int N)
{
    int t = blockIdx.x * 256 + threadIdx.x;
    if (t < N) { counts[t] = 1; fill[t] = 0; }
    if (t < C1) { colsum[t] = 0.f; colsq[t] = 0.f; }
}

// ---------------- GEMM1: H = x @ W1, fused s1/d1 (per-head attention dots) -
// 64x64 tile, BK=16, 256 threads, 4x4 outputs/thread. blockIdx.y = head,
// so a col-tile covers exactly one head's 64 channels -> s1/d1 computed
// fully in-block (no atomics).
__global__ __launch_bounds__(256)
void gemm1_kernel(const float* __restrict__ X, const float* __restrict__ W,
                  const float* __restrict__ as1, const float* __restrict__ ad1,
                  float* __restrict__ Hm, float* __restrict__ s1,
                  float* __restrict__ d1, int N)
{
    __shared__ float As[16][68];   // [k][row], padded: 272B row stride (16B aligned)
    __shared__ float Bs[16][68];   // [k][col]
    const int t    = threadIdx.x;
    const int tx   = t & 15;
    const int ty   = t >> 4;
    const int bm   = blockIdx.x * 64;
    const int head = blockIdx.y;
    const int bn   = head * 64;

    const int lrow = t >> 2;          // 0..63
    const int lk   = (t & 3) * 4;     // 0,4,8,12
    const int brow = t >> 4;          // 0..15
    const int bcol = (t & 15) * 4;    // 0..60

    float acc[4][4] = {};

    for (int k0 = 0; k0 < FIN; k0 += 16) {
        int ar = bm + lrow; if (ar > N - 1) ar = N - 1;
        float4 av = *(const float4*)(X + (size_t)ar * FIN + k0 + lk);
        float4 bv = *(const float4*)(W + (size_t)(k0 + brow) * C1 + bn + bcol);
        As[lk + 0][lrow] = av.x;
        As[lk + 1][lrow] = av.y;
        As[lk + 2][lrow] = av.z;
        As[lk + 3][lrow] = av.w;
        *(float4*)&Bs[brow][bcol] = bv;
        __syncthreads();
        #pragma unroll
        for (int kk = 0; kk < 16; ++kk) {
            float4 a = *(const float4*)&As[kk][ty * 4];
            float4 b = *(const float4*)&Bs[kk][tx * 4];
            float a4[4] = {a.x, a.y, a.z, a.w};
            float b4[4] = {b.x, b.y, b.z, b.w};
            #pragma unroll
            for (int i = 0; i < 4; ++i)
                #pragma unroll
                for (int j = 0; j < 4; ++j)
                    acc[i][j] += a4[i] * b4[j];
        }
        __syncthreads();
    }

    // epilogue: store C tile + per-row partial dots with a_src/a_dst
    float sp[4] = {0, 0, 0, 0}, dp[4] = {0, 0, 0, 0};
    #pragma unroll
    for (int i = 0; i < 4; ++i) {
        int row = bm + ty * 4 + i;
        if (row < N) {
            #pragma unroll
            for (int j = 0; j < 4; ++j) {
                int col = tx * 4 + j;
                float v = acc[i][j];
                Hm[(size_t)row * C1 + bn + col] = v;
                sp[i] += v * as1[bn + col];
                dp[i] += v * ad1[bn + col];
            }
        }
    }
    // reduce across the 16 tx lanes (lane bits 0..3)
    #pragma unroll
    for (int off = 1; off < 16; off <<= 1) {
        #pragma unroll
        for (int i = 0; i < 4; ++i) {
            sp[i] += __shfl_xor(sp[i], off);
            dp[i] += __shfl_xor(dp[i], off);
        }
    }
    if (tx == 0) {
        #pragma unroll
        for (int i = 0; i < 4; ++i) {
            int row = bm + ty * 4 + i;
            if (row < N) {
                s1[row * H1N + head] = sp[i];
                d1[row * H1N + head] = dp[i];
            }
        }
    }
}

// ---------------- CSR build ----------------------------------------------
__global__ __launch_bounds__(256)
void hist_kernel(const int* __restrict__ ei, const int* __restrict__ flag,
                 int* __restrict__ counts, int E)
{
    int t = blockIdx.x * 256 + threadIdx.x;
    int stride = flag[0];                       // 1=int32, 2=int64 (low word)
    if (t < E) atomicAdd(&counts[ei[(size_t)stride * (E + t)]], 1);
}

// single block, wave-shfl scans (3 barriers per 1024-chunk)
__global__ __launch_bounds__(1024)
void scan_kernel(const int* __restrict__ cnt, int* __restrict__ offs, int N)
{
    __shared__ int wsum[16];
    __shared__ int carry_s;
    const int t = threadIdx.x, lane = t & 63, w = t >> 6;
    if (t == 0) carry_s = 0;
    __syncthreads();
    for (int base = 0; base < N; base += 1024) {
        int idx = base + t;
        int v = (idx < N) ? cnt[idx] : 0;
        int incl = v;
        #pragma unroll
        for (int off = 1; off < 64; off <<= 1) {
            int u = __shfl_up(incl, off);
            if (lane >= off) incl += u;
        }
        if (lane == 63) wsum[w] = incl;
        __syncthreads();
        int wpre = 0;
        for (int i = 0; i < w; ++i) wpre += wsum[i];
        int c = carry_s;
        if (idx < N) offs[idx] = c + wpre + incl - v;   // exclusive
        __syncthreads();
        if (t == 1023) carry_s = c + wpre + incl;
        __syncthreads();
    }
    if (t == 0) offs[N] = carry_s;
}

__global__ __launch_bounds__(256)
void scatter_kernel(const int* __restrict__ ei, const int* __restrict__ flag,
                    const int* __restrict__ offs, int* __restrict__ fill,
                    int* __restrict__ ssrc, int E, int N)
{
    int t = blockIdx.x * 256 + threadIdx.x;
    if (t >= E + N) return;
    int stride = flag[0];
    int s, d;
    if (t < E) {
        s = ei[(size_t)stride * t];
        d = ei[(size_t)stride * (E + t)];
    } else {
        s = t - E; d = s;                        // self loop
    }
    int pos = offs[d] + atomicAdd(&fill[d], 1);
    ssrc[pos] = s;
}

// ---------------- layer-1 aggregate: block per dst node, thread per channel
__global__ __launch_bounds__(256)
void agg1_kernel(const float* __restrict__ Hm, const float* __restrict__ s1,
                 const float* __restrict__ d1, const int* __restrict__ offs,
                 const int* __restrict__ ssrc, const float* __restrict__ b1,
                 float* __restrict__ out1, int N)
{
    const int n = blockIdx.x;
    const int t = threadIdx.x;
    const int h = t >> 6;                 // head of this channel
    const int beg = offs[n], end = offs[n + 1];
    const float dh = d1[n * H1N + h];

    float m = -1e30f, denom = 0.f;        // online segment softmax (pass 1)
    for (int p = beg; p < end; ++p) {
        int s = ssrc[p];
        float e = s1[s * H1N + h] + dh;
        e = e > 0.f ? e : 0.2f * e;       // leaky_relu 0.2
        float mn = fmaxf(m, e);
        denom = denom * __expf(m - mn) + __expf(e - mn);
        m = mn;
    }
    float inv = 1.f / (denom + 1e-16f);

    float acc = 0.f;                      // pass 2: alpha-weighted gather
    for (int p = beg; p < end; ++p) {
        int s = ssrc[p];
        float e = s1[s * H1N + h] + dh;
        e = e > 0.f ? e : 0.2f * e;
        acc += Hm[(size_t)s * C1 + t] * (__expf(e - m) * inv);
    }
    out1[(size_t)n * C1 + t] = acc + b1[t];
}

// ---------------- BN column stats ----------------------------------------
__global__ __launch_bounds__(256)
void bnstats_kernel(const float* __restrict__ out1, float* __restrict__ colsum,
                    float* __restrict__ colsq, int N)
{
    int t = threadIdx.x;
    float s = 0.f, q = 0.f;
    for (int r = blockIdx.x; r < N; r += gridDim.x) {
        float v = out1[(size_t)r * C1 + t];
        s += v; q += v * v;
    }
    atomicAdd(&colsum[t], s);
    atomicAdd(&colsq[t], q);
}

__global__ __launch_bounds__(256)
void bnfin_kernel(const float* __restrict__ colsum, const float* __restrict__ colsq,
                  const float* __restrict__ gamma, const float* __restrict__ beta,
                  float* __restrict__ scale, float* __restrict__ shift, int N)
{
    int t = threadIdx.x;
    float mu  = colsum[t] / (float)N;
    float var = colsq[t] / (float)N - mu * mu;   // biased variance
    float sc  = gamma[t] * rsqrtf(var + 1e-5f);
    scale[t] = sc;
    shift[t] = beta[t] - mu * sc;
}

// ---------------- GEMM2 with fused BN+ELU on A-load, fused s2/d2 ----------
__global__ __launch_bounds__(320)
void gemm2_kernel(const float* __restrict__ out1, const float* __restrict__ scale,
                  const float* __restrict__ shift, const float* __restrict__ W2,
                  const float* __restrict__ as2, const float* __restrict__ ad2,
                  float* __restrict__ h2, float* __restrict__ s2,
                  float* __restrict__ d2, int N)
{
    __shared__ float Asm[16][65];
    __shared__ float Wsm[64 * NC];
    __shared__ float sred[16], dred[16];
    const int t  = threadIdx.x;
    const int rb = blockIdx.x * 16;
    const int j  = t % NC;       // output class
    const int rg = t / NC;       // 0..7 -> rows rg, rg+8
    if (t < 16) { sred[t] = 0.f; dred[t] = 0.f; }

    float acc0 = 0.f, acc1 = 0.f;
    for (int kc = 0; kc < C1; kc += 64) {
        for (int idx = t; idx < 16 * 64; idx += 320) {
            int r = idx >> 6, k = idx & 63;
            int row = rb + r;
            float v = 0.f;
            if (row < N) {
                v = out1[(size_t)row * C1 + kc + k];
                v = v * scale[kc + k] + shift[kc + k];
                v = v > 0.f ? v : (__expf(v) - 1.f);   // ELU
            }
            Asm[r][k] = v;
        }
        for (int idx = t; idx < 64 * NC; idx += 320)
            Wsm[idx] = W2[kc * NC + idx];
        __syncthreads();
        #pragma unroll 8
        for (int k = 0; k < 64; ++k) {
            float w = Wsm[k * NC + j];
            acc0 += Asm[rg][k]     * w;
            acc1 += Asm[rg + 8][k] * w;
        }
        __syncthreads();
    }
    int r0 = rb + rg, r1 = rb + rg + 8;
    if (r0 < N) h2[(size_t)r0 * NC + j] = acc0;
    if (r1 < N) h2[(size_t)r1 * NC + j] = acc1;
    float aj = as2[j], bj = ad2[j];
    atomicAdd(&sred[rg],     acc0 * aj);
    atomicAdd(&sred[rg + 8], acc1 * aj);
    atomicAdd(&dred[rg],     acc0 * bj);
    atomicAdd(&dred[rg + 8], acc1 * bj);
    __syncthreads();
    if (t < 16 && rb + t < N) { s2[rb + t] = sred[t]; d2[rb + t] = dred[t]; }
}

// ---------------- layer-2 aggregate + bias + log_softmax ------------------
__global__ __launch_bounds__(256)
void agg2_kernel(const float* __restrict__ h2, const float* __restrict__ s2,
                 const float* __restrict__ d2, const int* __restrict__ offs,
                 const int* __restrict__ ssrc, const float* __restrict__ b2,
                 float* __restrict__ out, int N)
{
    int node = blockIdx.x * 4 + (threadIdx.x >> 6);   // wave per node
    if (node >= N) return;
    int lane = threadIdx.x & 63;
    int beg = offs[node], end = offs[node + 1];
    float dn = d2[node];

    float m = -1e30f, denom = 0.f;
    for (int p = beg; p < end; ++p) {
        float e = s2[ssrc[p]] + dn;
        e = e > 0.f ? e : 0.2f * e;
        float mn = fmaxf(m, e);
        denom = denom * __expf(m - mn) + __expf(e - mn);
        m = mn;
    }
    float inv = 1.f / (denom + 1e-16f);

    int j = lane < NC ? lane : 0;
    float acc = 0.f;
    for (int p = beg; p < end; ++p) {
        int s = ssrc[p];
        float e = s2[s] + dn;
        e = e > 0.f ? e : 0.2f * e;
        acc += h2[(size_t)s * NC + j] * (__expf(e - m) * inv);
    }
    float v = acc + b2[j];

    float vm = lane < NC ? v : -1e30f;
    #pragma unroll
    for (int off = 32; off > 0; off >>= 1) vm = fmaxf(vm, __shfl_xor(vm, off));
    float ex = lane < NC ? __expf(v - vm) : 0.f;
    #pragma unroll
    for (int off = 32; off > 0; off >>= 1) ex += __shfl_xor(ex, off);
    if (lane < NC) out[(size_t)node * NC + lane] = v - vm - __logf(ex);
}

// ---------------- host ----------------------------------------------------
extern "C" void kernel_launch(void* const* d_in, const int* in_sizes, int n_in,
                              void* d_out, int out_size, void* d_ws, size_t ws_size,
                              hipStream_t stream)
{
    const float* x   = (const float*)d_in[0];
    const int*   ei  = (const int*)d_in[1];     // [2,E] int32 OR int64 (detected)
    const float* W1  = (const float*)d_in[2];
    const float* as1 = (const float*)d_in[3];
    const float* ad1 = (const float*)d_in[4];
    const float* b1  = (const float*)d_in[5];
    const float* gm  = (const float*)d_in[6];
    const float* bt  = (const float*)d_in[7];
    const float* W2  = (const float*)d_in[8];
    const float* as2 = (const float*)d_in[9];
    const float* ad2 = (const float*)d_in[10];
    const float* b2  = (const float*)d_in[11];
    const int N = in_sizes[0] / FIN;
    const int E = in_sizes[1] / 2;

    char* p = (char*)d_ws;
    auto take = [&](size_t bytes) {
        char* r = p; p += (bytes + 255) & ~(size_t)255; return r;
    };
    float* Hm     = (float*)take((size_t)N * C1 * 4);
    float* out1   = (float*)take((size_t)N * C1 * 4);
    float* h2     = (float*)take((size_t)N * NC * 4);
    float* s1     = (float*)take((size_t)N * H1N * 4);
    float* d1     = (float*)take((size_t)N * H1N * 4);
    float* s2     = (float*)take((size_t)N * 4);
    float* d2v    = (float*)take((size_t)N * 4);
    float* colsum = (float*)take(C1 * 4);
    float* colsq  = (float*)take(C1 * 4);
    float* bnsc   = (float*)take(C1 * 4);
    float* bnsh   = (float*)take(C1 * 4);
    int*   counts = (int*)take((size_t)N * 4);
    int*   offs   = (int*)take((size_t)(N + 1) * 4);
    int*   fill   = (int*)take((size_t)N * 4);
    int*   ssrc   = (int*)take((size_t)(E + N) * 4);
    int*   eflag  = (int*)take(256);

    detect_kernel<<<1, 64, 0, stream>>>(ei, eflag, E);
    init_kernel<<<(N + 255) / 256, 256, 0, stream>>>(counts, fill, colsum, colsq, N);
    gemm1_kernel<<<dim3((N + 63) / 64, H1N), 256, 0, stream>>>(x, W1, as1, ad1, Hm, s1, d1, N);
    hist_kernel<<<(E + 255) / 256, 256, 0, stream>>>(ei, eflag, counts, E);
    scan_kernel<<<1, 1024, 0, stream>>>(counts, offs, N);
    scatter_kernel<<<(E + N + 255) / 256, 256, 0, stream>>>(ei, eflag, offs, fill, ssrc, E, N);
    agg1_kernel<<<N, 256, 0, stream>>>(Hm, s1, d1, offs, ssrc, b1, out1, N);
    bnstats_kernel<<<256, 256, 0, stream>>>(out1, colsum, colsq, N);
    bnfin_kernel<<<1, 256, 0, stream>>>(colsum, colsq, gm, bt, bnsc, bnsh, N);
    gemm2_kernel<<<(N + 15) / 16, 320, 0, stream>>>(out1, bnsc, bnsh, W2, as2, ad2, h2, s2, d2v, N);
    agg2_kernel<<<(N + 3) / 4, 256, 0, stream>>>(h2, s2, d2v, offs, ssrc, b2, (float*)d_out, N);
}

// Round 4
// 672.446 us; speedup vs baseline: 1.0848x; 1.0848x over previous
//
#include <hip/hip_runtime.h>

constexpr int FIN = 256;   // input features
constexpr int C1  = 256;   // H1*hidden (layer-1 concat width)
constexpr int HID = 64;
constexpr int H1N = 4;
constexpr int NC  = 40;    // classes
constexpr int CAP = 256;   // agg1 LDS chunk (deg > CAP handled by chunk loop)

// ---------------- edge dtype detect: int32 vs int64 -----------------------
__global__ __launch_bounds__(64)
void detect_kernel(const int* __restrict__ ei, int* __restrict__ flag, int E)
{
    int lane = threadIdx.x;
    int q = lane * (E / 64);
    int v = ei[2 * q + 1];
    unsigned long long nz = __ballot(v != 0);
    if (lane == 0) flag[0] = (nz == 0ull) ? 2 : 1;
}

// ---------------- init ----------------------------------------------------
__global__ __launch_bounds__(256)
void init_kernel(int* __restrict__ counts, int* __restrict__ fill,
                 float* __restrict__ colsum, float* __restrict__ colsq, int N)
{
    int t = blockIdx.x * 256 + threadIdx.x;
    if (t < N) { counts[t] = 1; fill[t] = 0; }
    if (t < C1) { colsum[t] = 0.f; colsq[t] = 0.f; }
}

// ---------------- GEMM1: H = x @ W1, fused s1/d1 ---------------------------
__global__ __launch_bounds__(256)
void gemm1_kernel(const float* __restrict__ X, const float* __restrict__ W,
                  const float* __restrict__ as1, const float* __restrict__ ad1,
                  float* __restrict__ Hm, float* __restrict__ s1,
                  float* __restrict__ d1, int N)
{
    __shared__ float As[16][68];
    __shared__ float Bs[16][68];
    const int t    = threadIdx.x;
    const int tx   = t & 15;
    const int ty   = t >> 4;
    const int bm   = blockIdx.x * 64;
    const int head = blockIdx.y;
    const int bn   = head * 64;

    const int lrow = t >> 2;
    const int lk   = (t & 3) * 4;
    const int brow = t >> 4;
    const int bcol = (t & 15) * 4;

    float acc[4][4] = {};

    for (int k0 = 0; k0 < FIN; k0 += 16) {
        int ar = bm + lrow; if (ar > N - 1) ar = N - 1;
        float4 av = *(const float4*)(X + (size_t)ar * FIN + k0 + lk);
        float4 bv = *(const float4*)(W + (size_t)(k0 + brow) * C1 + bn + bcol);
        As[lk + 0][lrow] = av.x;
        As[lk + 1][lrow] = av.y;
        As[lk + 2][lrow] = av.z;
        As[lk + 3][lrow] = av.w;
        *(float4*)&Bs[brow][bcol] = bv;
        __syncthreads();
        #pragma unroll
        for (int kk = 0; kk < 16; ++kk) {
            float4 a = *(const float4*)&As[kk][ty * 4];
            float4 b = *(const float4*)&Bs[kk][tx * 4];
            float a4[4] = {a.x, a.y, a.z, a.w};
            float b4[4] = {b.x, b.y, b.z, b.w};
            #pragma unroll
            for (int i = 0; i < 4; ++i)
                #pragma unroll
                for (int j = 0; j < 4; ++j)
                    acc[i][j] += a4[i] * b4[j];
        }
        __syncthreads();
    }

    float sp[4] = {0, 0, 0, 0}, dp[4] = {0, 0, 0, 0};
    #pragma unroll
    for (int i = 0; i < 4; ++i) {
        int row = bm + ty * 4 + i;
        if (row < N) {
            #pragma unroll
            for (int j = 0; j < 4; ++j) {
                int col = tx * 4 + j;
                float v = acc[i][j];
                Hm[(size_t)row * C1 + bn + col] = v;
                sp[i] += v * as1[bn + col];
                dp[i] += v * ad1[bn + col];
            }
        }
    }
    #pragma unroll
    for (int off = 1; off < 16; off <<= 1) {
        #pragma unroll
        for (int i = 0; i < 4; ++i) {
            sp[i] += __shfl_xor(sp[i], off);
            dp[i] += __shfl_xor(dp[i], off);
        }
    }
    if (tx == 0) {
        #pragma unroll
        for (int i = 0; i < 4; ++i) {
            int row = bm + ty * 4 + i;
            if (row < N) {
                s1[row * H1N + head] = sp[i];
                d1[row * H1N + head] = dp[i];
            }
        }
    }
}

// ---------------- CSR build ----------------------------------------------
__global__ __launch_bounds__(256)
void hist_kernel(const int* __restrict__ ei, const int* __restrict__ flag,
                 int* __restrict__ counts, int E)
{
    int t = blockIdx.x * 256 + threadIdx.x;
    int stride = flag[0];
    if (t < E) atomicAdd(&counts[ei[(size_t)stride * (E + t)]], 1);
}

__global__ __launch_bounds__(1024)
void scan_kernel(const int* __restrict__ cnt, int* __restrict__ offs, int N)
{
    __shared__ int wsum[16];
    __shared__ int carry_s;
    const int t = threadIdx.x, lane = t & 63, w = t >> 6;
    if (t == 0) carry_s = 0;
    __syncthreads();
    for (int base = 0; base < N; base += 1024) {
        int idx = base + t;
        int v = (idx < N) ? cnt[idx] : 0;
        int incl = v;
        #pragma unroll
        for (int off = 1; off < 64; off <<= 1) {
            int u = __shfl_up(incl, off);
            if (lane >= off) incl += u;
        }
        if (lane == 63) wsum[w] = incl;
        __syncthreads();
        int wpre = 0;
        for (int i = 0; i < w; ++i) wpre += wsum[i];
        int c = carry_s;
        if (idx < N) offs[idx] = c + wpre + incl - v;
        __syncthreads();
        if (t == 1023) carry_s = c + wpre + incl;
        __syncthreads();
    }
    if (t == 0) offs[N] = carry_s;
}

__global__ __launch_bounds__(256)
void scatter_kernel(const int* __restrict__ ei, const int* __restrict__ flag,
                    const int* __restrict__ offs, int* __restrict__ fill,
                    int* __restrict__ ssrc, int E, int N)
{
    int t = blockIdx.x * 256 + threadIdx.x;
    if (t >= E + N) return;
    int stride = flag[0];
    int s, d;
    if (t < E) {
        s = ei[(size_t)stride * t];
        d = ei[(size_t)stride * (E + t)];
    } else {
        s = t - E; d = s;
    }
    int pos = offs[d] + atomicAdd(&fill[d], 1);
    ssrc[pos] = s;
}

// ---------------- layer-1 aggregate (v2) ----------------------------------
// Block per dst node. Wave w = head w. Lane-parallel segment max/sum via
// shfl reductions; exp(e-m) + src staged in LDS; gather pass is pure
// load+FMA, unrolled x4 for memory-pipeline depth.
__global__ __launch_bounds__(256)
void agg1_kernel(const float* __restrict__ Hm, const float* __restrict__ s1,
                 const float* __restrict__ d1, const int* __restrict__ offs,
                 const int* __restrict__ ssrc, const float* __restrict__ b1,
                 float* __restrict__ out1, int N)
{
    __shared__ float alpha[H1N][CAP];
    __shared__ int   srcs[CAP];
    __shared__ float invs[H1N];
    const int n    = blockIdx.x;
    const int t    = threadIdx.x;
    const int lane = t & 63;
    const int w    = t >> 6;              // wave index == head for stats
    const int beg  = offs[n], end = offs[n + 1];
    const int deg  = end - beg;
    const float dh = d1[n * H1N + w];

    // --- segment max (wave-parallel over edges) ---
    float mloc = -1e30f;
    for (int p = beg + lane; p < end; p += 64) {
        float e = s1[ssrc[p] * H1N + w] + dh;
        e = e > 0.f ? e : 0.2f * e;       // leaky_relu 0.2
        mloc = fmaxf(mloc, e);
    }
    #pragma unroll
    for (int off = 32; off; off >>= 1) mloc = fmaxf(mloc, __shfl_xor(mloc, off));

    // --- segment sum of exp(e - m) ---
    float ssum = 0.f;
    for (int p = beg + lane; p < end; p += 64) {
        float e = s1[ssrc[p] * H1N + w] + dh;
        e = e > 0.f ? e : 0.2f * e;
        ssum += __expf(e - mloc);
    }
    #pragma unroll
    for (int off = 32; off; off >>= 1) ssum += __shfl_xor(ssum, off);
    if (lane == 0) invs[w] = 1.f / (ssum + 1e-16f);

    // --- gather: chunk through CSR segment, alpha staged in LDS ---
    float acc0 = 0.f, acc1 = 0.f, acc2 = 0.f, acc3 = 0.f;
    for (int c0 = 0; c0 < deg; c0 += CAP) {
        int cnt = min(CAP, deg - c0);
        for (int i = lane; i < cnt; i += 64) {
            int p = beg + c0 + i;
            int s = ssrc[p];
            if (w == 0) srcs[i] = s;
            float e = s1[s * H1N + w] + dh;
            e = e > 0.f ? e : 0.2f * e;
            alpha[w][i] = __expf(e - mloc);
        }
        __syncthreads();
        int i = 0;
        for (; i + 4 <= cnt; i += 4) {
            int s0 = srcs[i],     s1i = srcs[i + 1];
            int s2 = srcs[i + 2], s3i = srcs[i + 3];
            float a0 = alpha[w][i],     a1 = alpha[w][i + 1];
            float a2 = alpha[w][i + 2], a3 = alpha[w][i + 3];
            float v0 = Hm[(size_t)s0  * C1 + t];
            float v1 = Hm[(size_t)s1i * C1 + t];
            float v2 = Hm[(size_t)s2  * C1 + t];
            float v3 = Hm[(size_t)s3i * C1 + t];
            acc0 += v0 * a0; acc1 += v1 * a1;
            acc2 += v2 * a2; acc3 += v3 * a3;
        }
        for (; i < cnt; ++i)
            acc0 += Hm[(size_t)srcs[i] * C1 + t] * alpha[w][i];
        __syncthreads();
    }
    float acc = (acc0 + acc1) + (acc2 + acc3);
    out1[(size_t)n * C1 + t] = acc * invs[w] + b1[t];
}

// ---------------- BN column stats ----------------------------------------
__global__ __launch_bounds__(256)
void bnstats_kernel(const float* __restrict__ out1, float* __restrict__ colsum,
                    float* __restrict__ colsq, int N)
{
    int t = threadIdx.x;
    float s = 0.f, q = 0.f;
    for (int r = blockIdx.x; r < N; r += gridDim.x) {
        float v = out1[(size_t)r * C1 + t];
        s += v; q += v * v;
    }
    atomicAdd(&colsum[t], s);
    atomicAdd(&colsq[t], q);
}

__global__ __launch_bounds__(256)
void bnfin_kernel(const float* __restrict__ colsum, const float* __restrict__ colsq,
                  const float* __restrict__ gamma, const float* __restrict__ beta,
                  float* __restrict__ scale, float* __restrict__ shift, int N)
{
    int t = threadIdx.x;
    float mu  = colsum[t] / (float)N;
    float var = colsq[t] / (float)N - mu * mu;
    float sc  = gamma[t] * rsqrtf(var + 1e-5f);
    scale[t] = sc;
    shift[t] = beta[t] - mu * sc;
}

// ---------------- GEMM2 with fused BN+ELU on A-load, fused s2/d2 ----------
__global__ __launch_bounds__(320)
void gemm2_kernel(const float* __restrict__ out1, const float* __restrict__ scale,
                  const float* __restrict__ shift, const float* __restrict__ W2,
                  const float* __restrict__ as2, const float* __restrict__ ad2,
                  float* __restrict__ h2, float* __restrict__ s2,
                  float* __restrict__ d2, int N)
{
    __shared__ float Asm[16][65];
    __shared__ float Wsm[64 * NC];
    __shared__ float sred[16], dred[16];
    const int t  = threadIdx.x;
    const int rb = blockIdx.x * 16;
    const int j  = t % NC;
    const int rg = t / NC;
    if (t < 16) { sred[t] = 0.f; dred[t] = 0.f; }

    float acc0 = 0.f, acc1 = 0.f;
    for (int kc = 0; kc < C1; kc += 64) {
        for (int idx = t; idx < 16 * 64; idx += 320) {
            int r = idx >> 6, k = idx & 63;
            int row = rb + r;
            float v = 0.f;
            if (row < N) {
                v = out1[(size_t)row * C1 + kc + k];
                v = v * scale[kc + k] + shift[kc + k];
                v = v > 0.f ? v : (__expf(v) - 1.f);   // ELU
            }
            Asm[r][k] = v;
        }
        for (int idx = t; idx < 64 * NC; idx += 320)
            Wsm[idx] = W2[kc * NC + idx];
        __syncthreads();
        #pragma unroll 8
        for (int k = 0; k < 64; ++k) {
            float w = Wsm[k * NC + j];
            acc0 += Asm[rg][k]     * w;
            acc1 += Asm[rg + 8][k] * w;
        }
        __syncthreads();
    }
    int r0 = rb + rg, r1 = rb + rg + 8;
    if (r0 < N) h2[(size_t)r0 * NC + j] = acc0;
    if (r1 < N) h2[(size_t)r1 * NC + j] = acc1;
    float aj = as2[j], bj = ad2[j];
    atomicAdd(&sred[rg],     acc0 * aj);
    atomicAdd(&sred[rg + 8], acc1 * aj);
    atomicAdd(&dred[rg],     acc0 * bj);
    atomicAdd(&dred[rg + 8], acc1 * bj);
    __syncthreads();
    if (t < 16 && rb + t < N) { s2[rb + t] = sred[t]; d2[rb + t] = dred[t]; }
}

// ---------------- layer-2 aggregate + bias + log_softmax ------------------
__global__ __launch_bounds__(256)
void agg2_kernel(const float* __restrict__ h2, const float* __restrict__ s2,
                 const float* __restrict__ d2, const int* __restrict__ offs,
                 const int* __restrict__ ssrc, const float* __restrict__ b2,
                 float* __restrict__ out, int N)
{
    int node = blockIdx.x * 4 + (threadIdx.x >> 6);
    if (node >= N) return;
    int lane = threadIdx.x & 63;
    int beg = offs[node], end = offs[node + 1];
    float dn = d2[node];

    float m = -1e30f, denom = 0.f;
    for (int p = beg; p < end; ++p) {
        float e = s2[ssrc[p]] + dn;
        e = e > 0.f ? e : 0.2f * e;
        float mn = fmaxf(m, e);
        denom = denom * __expf(m - mn) + __expf(e - mn);
        m = mn;
    }
    float inv = 1.f / (denom + 1e-16f);

    int j = lane < NC ? lane : 0;
    float acc = 0.f;
    for (int p = beg; p < end; ++p) {
        int s = ssrc[p];
        float e = s2[s] + dn;
        e = e > 0.f ? e : 0.2f * e;
        acc += h2[(size_t)s * NC + j] * (__expf(e - m) * inv);
    }
    float v = acc + b2[j];

    float vm = lane < NC ? v : -1e30f;
    #pragma unroll
    for (int off = 32; off > 0; off >>= 1) vm = fmaxf(vm, __shfl_xor(vm, off));
    float ex = lane < NC ? __expf(v - vm) : 0.f;
    #pragma unroll
    for (int off = 32; off > 0; off >>= 1) ex += __shfl_xor(ex, off);
    if (lane < NC) out[(size_t)node * NC + lane] = v - vm - __logf(ex);
}

// ---------------- host ----------------------------------------------------
extern "C" void kernel_launch(void* const* d_in, const int* in_sizes, int n_in,
                              void* d_out, int out_size, void* d_ws, size_t ws_size,
                              hipStream_t stream)
{
    const float* x   = (const float*)d_in[0];
    const int*   ei  = (const int*)d_in[1];
    const float* W1  = (const float*)d_in[2];
    const float* as1 = (const float*)d_in[3];
    const float* ad1 = (const float*)d_in[4];
    const float* b1  = (const float*)d_in[5];
    const float* gm  = (const float*)d_in[6];
    const float* bt  = (const float*)d_in[7];
    const float* W2  = (const float*)d_in[8];
    const float* as2 = (const float*)d_in[9];
    const float* ad2 = (const float*)d_in[10];
    const float* b2  = (const float*)d_in[11];
    const int N = in_sizes[0] / FIN;
    const int E = in_sizes[1] / 2;

    char* p = (char*)d_ws;
    auto take = [&](size_t bytes) {
        char* r = p; p += (bytes + 255) & ~(size_t)255; return r;
    };
    float* Hm     = (float*)take((size_t)N * C1 * 4);
    float* out1   = (float*)take((size_t)N * C1 * 4);
    float* h2     = (float*)take((size_t)N * NC * 4);
    float* s1     = (float*)take((size_t)N * H1N * 4);
    float* d1     = (float*)take((size_t)N * H1N * 4);
    float* s2     = (float*)take((size_t)N * 4);
    float* d2v    = (float*)take((size_t)N * 4);
    float* colsum = (float*)take(C1 * 4);
    float* colsq  = (float*)take(C1 * 4);
    float* bnsc   = (float*)take(C1 * 4);
    float* bnsh   = (float*)take(C1 * 4);
    int*   counts = (int*)take((size_t)N * 4);
    int*   offs   = (int*)take((size_t)(N + 1) * 4);
    int*   fill   = (int*)take((size_t)N * 4);
    int*   ssrc   = (int*)take((size_t)(E + N) * 4);
    int*   eflag  = (int*)take(256);

    detect_kernel<<<1, 64, 0, stream>>>(ei, eflag, E);
    init_kernel<<<(N + 255) / 256, 256, 0, stream>>>(counts, fill, colsum, colsq, N);
    gemm1_kernel<<<dim3((N + 63) / 64, H1N), 256, 0, stream>>>(x, W1, as1, ad1, Hm, s1, d1, N);
    hist_kernel<<<(E + 255) / 256, 256, 0, stream>>>(ei, eflag, counts, E);
    scan_kernel<<<1, 1024, 0, stream>>>(counts, offs, N);
    scatter_kernel<<<(E + N + 255) / 256, 256, 0, stream>>>(ei, eflag, offs, fill, ssrc, E, N);
    agg1_kernel<<<N, 256, 0, stream>>>(Hm, s1, d1, offs, ssrc, b1, out1, N);
    bnstats_kernel<<<256, 256, 0, stream>>>(out1, colsum, colsq, N);
    bnfin_kernel<<<1, 256, 0, stream>>>(colsum, colsq, gm, bt, bnsc, bnsh, N);
    gemm2_kernel<<<(N + 15) / 16, 320, 0, stream>>>(out1, bnsc, bnsh, W2, as2, ad2, h2, s2, d2v, N);
    agg2_kernel<<<(N + 3) / 4, 256, 0, stream>>>(h2, s2, d2v, offs, ssrc, b2, (float*)d_out, N);
}

// Round 7
// 563.315 us; speedup vs baseline: 1.2949x; 1.1937x over previous
//
#include <hip/hip_runtime.h>
#include <hip/hip_fp16.h>

constexpr int FIN = 256;   // input features
constexpr int C1  = 256;   // H1*hidden (layer-1 concat width)
constexpr int HID = 64;
constexpr int H1N = 4;
constexpr int NC  = 40;    // classes
constexpr int CAP = 256;   // agg1 LDS chunk (deg > CAP handled by fallback)
constexpr int CAP2 = 128;  // agg2 per-wave LDS capacity

// ---------------- edge dtype detect: int32 vs int64 -----------------------
__global__ __launch_bounds__(64)
void detect_kernel(const int* __restrict__ ei, int* __restrict__ flag, int E)
{
    int lane = threadIdx.x;
    int q = lane * (E / 64);
    int v = ei[2 * q + 1];
    unsigned long long nz = __ballot(v != 0);
    if (lane == 0) flag[0] = (nz == 0ull) ? 2 : 1;
}

// ---------------- init ----------------------------------------------------
__global__ __launch_bounds__(256)
void init_kernel(int* __restrict__ counts, int* __restrict__ fill,
                 float* __restrict__ colsum, float* __restrict__ colsq, int N)
{
    int t = blockIdx.x * 256 + threadIdx.x;
    if (t < N) { counts[t] = 1; fill[t] = 0; }
    if (t < C1) { colsum[t] = 0.f; colsq[t] = 0.f; }
}

// ---------------- GEMM1: H = x @ W1 (fp16 out), fused s1/d1 ----------------
__global__ __launch_bounds__(256)
void gemm1_kernel(const float* __restrict__ X, const float* __restrict__ W,
                  const float* __restrict__ as1, const float* __restrict__ ad1,
                  __half* __restrict__ Hm, float* __restrict__ s1,
                  float* __restrict__ d1, int N)
{
    __shared__ float As[16][68];
    __shared__ float Bs[16][68];
    const int t    = threadIdx.x;
    const int tx   = t & 15;
    const int ty   = t >> 4;
    const int bm   = blockIdx.x * 64;
    const int head = blockIdx.y;
    const int bn   = head * 64;

    const int lrow = t >> 2;
    const int lk   = (t & 3) * 4;
    const int brow = t >> 4;
    const int bcol = (t & 15) * 4;

    float acc[4][4] = {};

    for (int k0 = 0; k0 < FIN; k0 += 16) {
        int ar = bm + lrow; if (ar > N - 1) ar = N - 1;
        float4 av = *(const float4*)(X + (size_t)ar * FIN + k0 + lk);
        float4 bv = *(const float4*)(W + (size_t)(k0 + brow) * C1 + bn + bcol);
        As[lk + 0][lrow] = av.x;
        As[lk + 1][lrow] = av.y;
        As[lk + 2][lrow] = av.z;
        As[lk + 3][lrow] = av.w;
        *(float4*)&Bs[brow][bcol] = bv;
        __syncthreads();
        #pragma unroll
        for (int kk = 0; kk < 16; ++kk) {
            float4 a = *(const float4*)&As[kk][ty * 4];
            float4 b = *(const float4*)&Bs[kk][tx * 4];
            float a4[4] = {a.x, a.y, a.z, a.w};
            float b4[4] = {b.x, b.y, b.z, b.w};
            #pragma unroll
            for (int i = 0; i < 4; ++i)
                #pragma unroll
                for (int j = 0; j < 4; ++j)
                    acc[i][j] += a4[i] * b4[j];
        }
        __syncthreads();
    }

    float sp[4] = {0, 0, 0, 0}, dp[4] = {0, 0, 0, 0};
    #pragma unroll
    for (int i = 0; i < 4; ++i) {
        int row = bm + ty * 4 + i;
        if (row < N) {
            // pack 4 consecutive cols to half4 (8B store, aligned)
            __half2 p01 = __floats2half2_rn(acc[i][0], acc[i][1]);
            __half2 p23 = __floats2half2_rn(acc[i][2], acc[i][3]);
            uint2 pk;
            pk.x = *(unsigned int*)&p01;
            pk.y = *(unsigned int*)&p23;
            *(uint2*)(Hm + (size_t)row * C1 + bn + tx * 4) = pk;
            #pragma unroll
            for (int j = 0; j < 4; ++j) {
                int col = tx * 4 + j;
                float v = acc[i][j];
                sp[i] += v * as1[bn + col];
                dp[i] += v * ad1[bn + col];
            }
        }
    }
    #pragma unroll
    for (int off = 1; off < 16; off <<= 1) {
        #pragma unroll
        for (int i = 0; i < 4; ++i) {
            sp[i] += __shfl_xor(sp[i], off);
            dp[i] += __shfl_xor(dp[i], off);
        }
    }
    if (tx == 0) {
        #pragma unroll
        for (int i = 0; i < 4; ++i) {
            int row = bm + ty * 4 + i;
            if (row < N) {
                s1[row * H1N + head] = sp[i];
                d1[row * H1N + head] = dp[i];
            }
        }
    }
}

// ---------------- CSR build ----------------------------------------------
__global__ __launch_bounds__(256)
void hist_kernel(const int* __restrict__ ei, const int* __restrict__ flag,
                 int* __restrict__ counts, int E)
{
    int t = blockIdx.x * 256 + threadIdx.x;
    int stride = flag[0];
    if (t < E) atomicAdd(&counts[ei[(size_t)stride * (E + t)]], 1);
}

__global__ __launch_bounds__(1024)
void scan_kernel(const int* __restrict__ cnt, int* __restrict__ offs, int N)
{
    __shared__ int wsum[16];
    __shared__ int carry_s;
    const int t = threadIdx.x, lane = t & 63, w = t >> 6;
    if (t == 0) carry_s = 0;
    __syncthreads();
    for (int base = 0; base < N; base += 1024) {
        int idx = base + t;
        int v = (idx < N) ? cnt[idx] : 0;
        int incl = v;
        #pragma unroll
        for (int off = 1; off < 64; off <<= 1) {
            int u = __shfl_up(incl, off);
            if (lane >= off) incl += u;
        }
        if (lane == 63) wsum[w] = incl;
        __syncthreads();
        int wpre = 0;
        for (int i = 0; i < w; ++i) wpre += wsum[i];
        int c = carry_s;
        if (idx < N) offs[idx] = c + wpre + incl - v;
        __syncthreads();
        if (t == 1023) carry_s = c + wpre + incl;
        __syncthreads();
    }
    if (t == 0) offs[N] = carry_s;
}

__global__ __launch_bounds__(256)
void scatter_kernel(const int* __restrict__ ei, const int* __restrict__ flag,
                    const int* __restrict__ offs, int* __restrict__ fill,
                    int* __restrict__ ssrc, int E, int N)
{
    int t = blockIdx.x * 256 + threadIdx.x;
    if (t >= E + N) return;
    int stride = flag[0];
    int s, d;
    if (t < E) {
        s = ei[(size_t)stride * t];
        d = ei[(size_t)stride * (E + t)];
    } else {
        s = t - E; d = s;
    }
    int pos = offs[d] + atomicAdd(&fill[d], 1);
    ssrc[pos] = s;
}

// ---------------- layer-1 aggregate (v3) ----------------------------------
// fp16 Hm gather (half the bytes); single-pass stats: e staged in LDS during
// the max pass, exp/sum from LDS (2 of 3 s1-gather passes eliminated).
__global__ __launch_bounds__(256)
void agg1_kernel(const __half* __restrict__ Hm, const float* __restrict__ s1,
                 const float* __restrict__ d1, const int* __restrict__ offs,
                 const int* __restrict__ ssrc, const float* __restrict__ b1,
                 float* __restrict__ out1, int N)
{
    __shared__ float alpha[H1N][CAP];
    __shared__ int   srcs[CAP];
    __shared__ float invs[H1N];
    const int n    = blockIdx.x;
    const int t    = threadIdx.x;
    const int lane = t & 63;
    const int w    = t >> 6;              // wave index == head for stats
    const int beg  = offs[n], end = offs[n + 1];
    const int deg  = end - beg;
    const float dh = d1[n * H1N + w];

    if (deg <= CAP) {
        // ---- fast path: stage e, one s1 pass ----
        float mloc = -1e30f;
        for (int i = lane; i < deg; i += 64) {
            int s = ssrc[beg + i];
            if (w == 0) srcs[i] = s;
            float e = s1[s * H1N + w] + dh;
            e = e > 0.f ? e : 0.2f * e;   // leaky_relu 0.2
            alpha[w][i] = e;
            mloc = fmaxf(mloc, e);
        }
        #pragma unroll
        for (int off = 32; off; off >>= 1) mloc = fmaxf(mloc, __shfl_xor(mloc, off));
        float ssum = 0.f;
        for (int i = lane; i < deg; i += 64) {
            float ex = __expf(alpha[w][i] - mloc);
            alpha[w][i] = ex;
            ssum += ex;
        }
        #pragma unroll
        for (int off = 32; off; off >>= 1) ssum += __shfl_xor(ssum, off);
        if (lane == 0) invs[w] = 1.f / (ssum + 1e-16f);
        __syncthreads();

        float acc0 = 0.f, acc1 = 0.f, acc2 = 0.f, acc3 = 0.f;
        int i = 0;
        for (; i + 4 <= deg; i += 4) {
            int s0 = srcs[i],     s1i = srcs[i + 1];
            int s2 = srcs[i + 2], s3i = srcs[i + 3];
            float a0 = alpha[w][i],     a1 = alpha[w][i + 1];
            float a2 = alpha[w][i + 2], a3 = alpha[w][i + 3];
            float v0 = __half2float(Hm[(size_t)s0  * C1 + t]);
            float v1 = __half2float(Hm[(size_t)s1i * C1 + t]);
            float v2 = __half2float(Hm[(size_t)s2  * C1 + t]);
            float v3 = __half2float(Hm[(size_t)s3i * C1 + t]);
            acc0 += v0 * a0; acc1 += v1 * a1;
            acc2 += v2 * a2; acc3 += v3 * a3;
        }
        for (; i < deg; ++i)
            acc0 += __half2float(Hm[(size_t)srcs[i] * C1 + t]) * alpha[w][i];
        float acc = (acc0 + acc1) + (acc2 + acc3);
        out1[(size_t)n * C1 + t] = acc * invs[w] + b1[t];
        return;
    }

    // ---- fallback: deg > CAP (3-pass, chunked) ----
    float mloc = -1e30f;
    for (int p = beg + lane; p < end; p += 64) {
        float e = s1[ssrc[p] * H1N + w] + dh;
        e = e > 0.f ? e : 0.2f * e;
        mloc = fmaxf(mloc, e);
    }
    #pragma unroll
    for (int off = 32; off; off >>= 1) mloc = fmaxf(mloc, __shfl_xor(mloc, off));
    float ssum = 0.f;
    for (int p = beg + lane; p < end; p += 64) {
        float e = s1[ssrc[p] * H1N + w] + dh;
        e = e > 0.f ? e : 0.2f * e;
        ssum += __expf(e - mloc);
    }
    #pragma unroll
    for (int off = 32; off; off >>= 1) ssum += __shfl_xor(ssum, off);
    if (lane == 0) invs[w] = 1.f / (ssum + 1e-16f);

    float acc0 = 0.f, acc1 = 0.f, acc2 = 0.f, acc3 = 0.f;
    for (int c0 = 0; c0 < deg; c0 += CAP) {
        int cnt = min(CAP, deg - c0);
        for (int i = lane; i < cnt; i += 64) {
            int p = beg + c0 + i;
            int s = ssrc[p];
            if (w == 0) srcs[i] = s;
            float e = s1[s * H1N + w] + dh;
            e = e > 0.f ? e : 0.2f * e;
            alpha[w][i] = __expf(e - mloc);
        }
        __syncthreads();
        int i = 0;
        for (; i + 4 <= cnt; i += 4) {
            int s0 = srcs[i],     s1i = srcs[i + 1];
            int s2 = srcs[i + 2], s3i = srcs[i + 3];
            float a0 = alpha[w][i],     a1 = alpha[w][i + 1];
            float a2 = alpha[w][i + 2], a3 = alpha[w][i + 3];
            float v0 = __half2float(Hm[(size_t)s0  * C1 + t]);
            float v1 = __half2float(Hm[(size_t)s1i * C1 + t]);
            float v2 = __half2float(Hm[(size_t)s2  * C1 + t]);
            float v3 = __half2float(Hm[(size_t)s3i * C1 + t]);
            acc0 += v0 * a0; acc1 += v1 * a1;
            acc2 += v2 * a2; acc3 += v3 * a3;
        }
        for (; i < cnt; ++i)
            acc0 += __half2float(Hm[(size_t)srcs[i] * C1 + t]) * alpha[w][i];
        __syncthreads();
    }
    float acc = (acc0 + acc1) + (acc2 + acc3);
    out1[(size_t)n * C1 + t] = acc * invs[w] + b1[t];
}

// ---------------- BN column stats ----------------------------------------
__global__ __launch_bounds__(256)
void bnstats_kernel(const float* __restrict__ out1, float* __restrict__ colsum,
                    float* __restrict__ colsq, int N)
{
    int t = threadIdx.x;
    float s = 0.f, q = 0.f;
    for (int r = blockIdx.x; r < N; r += gridDim.x) {
        float v = out1[(size_t)r * C1 + t];
        s += v; q += v * v;
    }
    atomicAdd(&colsum[t], s);
    atomicAdd(&colsq[t], q);
}

__global__ __launch_bounds__(256)
void bnfin_kernel(const float* __restrict__ colsum, const float* __restrict__ colsq,
                  const float* __restrict__ gamma, const float* __restrict__ beta,
                  float* __restrict__ scale, float* __restrict__ shift, int N)
{
    int t = threadIdx.x;
    float mu  = colsum[t] / (float)N;
    float var = colsq[t] / (float)N - mu * mu;
    float sc  = gamma[t] * rsqrtf(var + 1e-5f);
    scale[t] = sc;
    shift[t] = beta[t] - mu * sc;
}

// ---------------- GEMM2 with fused BN+ELU on A-load, fused s2/d2 ----------
__global__ __launch_bounds__(320)
void gemm2_kernel(const float* __restrict__ out1, const float* __restrict__ scale,
                  const float* __restrict__ shift, const float* __restrict__ W2,
                  const float* __restrict__ as2, const float* __restrict__ ad2,
                  float* __restrict__ h2, float* __restrict__ s2,
                  float* __restrict__ d2, int N)
{
    __shared__ float Asm[16][65];
    __shared__ float Wsm[64 * NC];
    __shared__ float sred[16], dred[16];
    const int t  = threadIdx.x;
    const int rb = blockIdx.x * 16;
    const int j  = t % NC;
    const int rg = t / NC;
    if (t < 16) { sred[t] = 0.f; dred[t] = 0.f; }

    float acc0 = 0.f, acc1 = 0.f;
    for (int kc = 0; kc < C1; kc += 64) {
        for (int idx = t; idx < 16 * 64; idx += 320) {
            int r = idx >> 6, k = idx & 63;
            int row = rb + r;
            float v = 0.f;
            if (row < N) {
                v = out1[(size_t)row * C1 + kc + k];
                v = v * scale[kc + k] + shift[kc + k];
                v = v > 0.f ? v : (__expf(v) - 1.f);   // ELU
            }
            Asm[r][k] = v;
        }
        for (int idx = t; idx < 64 * NC; idx += 320)
            Wsm[idx] = W2[kc * NC + idx];
        __syncthreads();
        #pragma unroll 8
        for (int k = 0; k < 64; ++k) {
            float w = Wsm[k * NC + j];
            acc0 += Asm[rg][k]     * w;
            acc1 += Asm[rg + 8][k] * w;
        }
        __syncthreads();
    }
    int r0 = rb + rg, r1 = rb + rg + 8;
    if (r0 < N) h2[(size_t)r0 * NC + j] = acc0;
    if (r1 < N) h2[(size_t)r1 * NC + j] = acc1;
    float aj = as2[j], bj = ad2[j];
    atomicAdd(&sred[rg],     acc0 * aj);
    atomicAdd(&sred[rg + 8], acc1 * aj);
    atomicAdd(&dred[rg],     acc0 * bj);
    atomicAdd(&dred[rg + 8], acc1 * bj);
    __syncthreads();
    if (t < 16 && rb + t < N) { s2[rb + t] = sred[t]; d2[rb + t] = dred[t]; }
}

// ---------------- layer-2 aggregate (v2) + bias + log_softmax --------------
// Wave per node. Lane-parallel stats via shfl (replaces serial online chain);
// alpha/src staged in per-wave LDS slabs (wave-coherent, no barriers);
// gather unrolled x4. deg > CAP2 falls back to the serial path.
__global__ __launch_bounds__(256)
void agg2_kernel(const float* __restrict__ h2, const float* __restrict__ s2,
                 const float* __restrict__ d2, const int* __restrict__ offs,
                 const int* __restrict__ ssrc, const float* __restrict__ b2,
                 float* __restrict__ out, int N)
{
    __shared__ float al[4][CAP2];
    __shared__ int   sr[4][CAP2];
    int w = threadIdx.x >> 6;
    int node = blockIdx.x * 4 + w;
    if (node >= N) return;
    int lane = threadIdx.x & 63;
    int beg = offs[node], end = offs[node + 1];
    int deg = end - beg;
    float dn = d2[node];

    float v;
    if (deg <= CAP2) {
        // lane-parallel stats, staged e
        float mloc = -1e30f;
        for (int i = lane; i < deg; i += 64) {
            int s = ssrc[beg + i];
            sr[w][i] = s;
            float e = s2[s] + dn;
            e = e > 0.f ? e : 0.2f * e;
            al[w][i] = e;
            mloc = fmaxf(mloc, e);
        }
        #pragma unroll
        for (int off = 32; off; off >>= 1) mloc = fmaxf(mloc, __shfl_xor(mloc, off));
        float ssum = 0.f;
        for (int i = lane; i < deg; i += 64) {
            float ex = __expf(al[w][i] - mloc);
            al[w][i] = ex;
            ssum += ex;
        }
        #pragma unroll
        for (int off = 32; off; off >>= 1) ssum += __shfl_xor(ssum, off);
        float inv = 1.f / (ssum + 1e-16f);

        int j = lane < NC ? lane : 0;
        float acc0 = 0.f, acc1 = 0.f, acc2 = 0.f, acc3 = 0.f;
        int i = 0;
        for (; i + 4 <= deg; i += 4) {
            float a0 = al[w][i],     a1 = al[w][i + 1];
            float a2 = al[w][i + 2], a3 = al[w][i + 3];
            acc0 += h2[(size_t)sr[w][i]     * NC + j] * a0;
            acc1 += h2[(size_t)sr[w][i + 1] * NC + j] * a1;
            acc2 += h2[(size_t)sr[w][i + 2] * NC + j] * a2;
            acc3 += h2[(size_t)sr[w][i + 3] * NC + j] * a3;
        }
        for (; i < deg; ++i)
            acc0 += h2[(size_t)sr[w][i] * NC + j] * al[w][i];
        v = ((acc0 + acc1) + (acc2 + acc3)) * inv + b2[j];
    } else {
        // fallback: serial online softmax (exact, rare)
        float m = -1e30f, denom = 0.f;
        for (int p = beg; p < end; ++p) {
            float e = s2[ssrc[p]] + dn;
            e = e > 0.f ? e : 0.2f * e;
            float mn = fmaxf(m, e);
            denom = denom * __expf(m - mn) + __expf(e - mn);
            m = mn;
        }
        float inv = 1.f / (denom + 1e-16f);
        int j = lane < NC ? lane : 0;
        float acc = 0.f;
        for (int p = beg; p < end; ++p) {
            int s = ssrc[p];
            float e = s2[s] + dn;
            e = e > 0.f ? e : 0.2f * e;
            acc += h2[(size_t)s * NC + j] * (__expf(e - m) * inv);
        }
        v = acc + b2[j];
    }

    float vm = lane < NC ? v : -1e30f;
    #pragma unroll
    for (int off = 32; off > 0; off >>= 1) vm = fmaxf(vm, __shfl_xor(vm, off));
    float ex = lane < NC ? __expf(v - vm) : 0.f;
    #pragma unroll
    for (int off = 32; off > 0; off >>= 1) ex += __shfl_xor(ex, off);
    if (lane < NC) out[(size_t)node * NC + lane] = v - vm - __logf(ex);
}

// ---------------- host ----------------------------------------------------
extern "C" void kernel_launch(void* const* d_in, const int* in_sizes, int n_in,
                              void* d_out, int out_size, void* d_ws, size_t ws_size,
                              hipStream_t stream)
{
    const float* x   = (const float*)d_in[0];
    const int*   ei  = (const int*)d_in[1];
    const float* W1  = (const float*)d_in[2];
    const float* as1 = (const float*)d_in[3];
    const float* ad1 = (const float*)d_in[4];
    const float* b1  = (const float*)d_in[5];
    const float* gm  = (const float*)d_in[6];
    const float* bt  = (const float*)d_in[7];
    const float* W2  = (const float*)d_in[8];
    const float* as2 = (const float*)d_in[9];
    const float* ad2 = (const float*)d_in[10];
    const float* b2  = (const float*)d_in[11];
    const int N = in_sizes[0] / FIN;
    const int E = in_sizes[1] / 2;

    char* p = (char*)d_ws;
    auto take = [&](size_t bytes) {
        char* r = p; p += (bytes + 255) & ~(size_t)255; return r;
    };
    __half* Hm    = (__half*)take((size_t)N * C1 * 2);
    float* out1   = (float*)take((size_t)N * C1 * 4);
    float* h2     = (float*)take((size_t)N * NC * 4);
    float* s1     = (float*)take((size_t)N * H1N * 4);
    float* d1     = (float*)take((size_t)N * H1N * 4);
    float* s2     = (float*)take((size_t)N * 4);
    float* d2v    = (float*)take((size_t)N * 4);
    float* colsum = (float*)take(C1 * 4);
    float* colsq  = (float*)take(C1 * 4);
    float* bnsc   = (float*)take(C1 * 4);
    float* bnsh   = (float*)take(C1 * 4);
    int*   counts = (int*)take((size_t)N * 4);
    int*   offs   = (int*)take((size_t)(N + 1) * 4);
    int*   fill   = (int*)take((size_t)N * 4);
    int*   ssrc   = (int*)take((size_t)(E + N) * 4);
    int*   eflag  = (int*)take(256);

    detect_kernel<<<1, 64, 0, stream>>>(ei, eflag, E);
    init_kernel<<<(N + 255) / 256, 256, 0, stream>>>(counts, fill, colsum, colsq, N);
    gemm1_kernel<<<dim3((N + 63) / 64, H1N), 256, 0, stream>>>(x, W1, as1, ad1, Hm, s1, d1, N);
    hist_kernel<<<(E + 255) / 256, 256, 0, stream>>>(ei, eflag, counts, E);
    scan_kernel<<<1, 1024, 0, stream>>>(counts, offs, N);
    scatter_kernel<<<(E + N + 255) / 256, 256, 0, stream>>>(ei, eflag, offs, fill, ssrc, E, N);
    agg1_kernel<<<N, 256, 0, stream>>>(Hm, s1, d1, offs, ssrc, b1, out1, N);
    bnstats_kernel<<<256, 256, 0, stream>>>(out1, colsum, colsq, N);
    bnfin_kernel<<<1, 256, 0, stream>>>(colsum, colsq, gm, bt, bnsc, bnsh, N);
    gemm2_kernel<<<(N + 15) / 16, 320, 0, stream>>>(out1, bnsc, bnsh, W2, as2, ad2, h2, s2, d2v, N);
    agg2_kernel<<<(N + 3) / 4, 256, 0, stream>>>(h2, s2, d2v, offs, ssrc, b2, (float*)d_out, N);
}

// Round 9
// 495.072 us; speedup vs baseline: 1.4734x; 1.1378x over previous
//
#include <hip/hip_runtime.h>
#include <hip/hip_fp16.h>

constexpr int FIN = 256;   // input features
constexpr int C1  = 256;   // H1*hidden (layer-1 concat width)
constexpr int HID = 64;
constexpr int H1N = 4;
constexpr int NC  = 40;    // classes
constexpr int CAP = 256;   // agg1 LDS chunk (deg > CAP handled by fallback)
constexpr int CAP2 = 128;  // agg2 per-wave LDS capacity

// ---------------- edge dtype detect: int32 vs int64 -----------------------
__global__ __launch_bounds__(64)
void detect_kernel(const int* __restrict__ ei, int* __restrict__ flag, int E)
{
    int lane = threadIdx.x;
    int q = lane * (E / 64);
    int v = ei[2 * q + 1];
    unsigned long long nz = __ballot(v != 0);
    if (lane == 0) flag[0] = (nz == 0ull) ? 2 : 1;
}

// ---------------- init ----------------------------------------------------
__global__ __launch_bounds__(256)
void init_kernel(int* __restrict__ counts, int* __restrict__ fill,
                 float* __restrict__ colsum, float* __restrict__ colsq, int N)
{
    int t = blockIdx.x * 256 + threadIdx.x;
    if (t < N) { counts[t] = 1; fill[t] = 0; }
    if (t < C1) { colsum[t] = 0.f; colsq[t] = 0.f; }
}

// ---------------- GEMM1: H = x @ W1 (fp16 out), fused s1/d1 ----------------
__global__ __launch_bounds__(256)
void gemm1_kernel(const float* __restrict__ X, const float* __restrict__ W,
                  const float* __restrict__ as1, const float* __restrict__ ad1,
                  __half* __restrict__ Hm, float* __restrict__ s1,
                  float* __restrict__ d1, int N)
{
    __shared__ float As[16][68];
    __shared__ float Bs[16][68];
    const int t    = threadIdx.x;
    const int tx   = t & 15;
    const int ty   = t >> 4;
    const int bm   = blockIdx.x * 64;
    const int head = blockIdx.y;
    const int bn   = head * 64;

    const int lrow = t >> 2;
    const int lk   = (t & 3) * 4;
    const int brow = t >> 4;
    const int bcol = (t & 15) * 4;

    float acc[4][4] = {};

    for (int k0 = 0; k0 < FIN; k0 += 16) {
        int ar = bm + lrow; if (ar > N - 1) ar = N - 1;
        float4 av = *(const float4*)(X + (size_t)ar * FIN + k0 + lk);
        float4 bv = *(const float4*)(W + (size_t)(k0 + brow) * C1 + bn + bcol);
        As[lk + 0][lrow] = av.x;
        As[lk + 1][lrow] = av.y;
        As[lk + 2][lrow] = av.z;
        As[lk + 3][lrow] = av.w;
        *(float4*)&Bs[brow][bcol] = bv;
        __syncthreads();
        #pragma unroll
        for (int kk = 0; kk < 16; ++kk) {
            float4 a = *(const float4*)&As[kk][ty * 4];
            float4 b = *(const float4*)&Bs[kk][tx * 4];
            float a4[4] = {a.x, a.y, a.z, a.w};
            float b4[4] = {b.x, b.y, b.z, b.w};
            #pragma unroll
            for (int i = 0; i < 4; ++i)
                #pragma unroll
                for (int j = 0; j < 4; ++j)
                    acc[i][j] += a4[i] * b4[j];
        }
        __syncthreads();
    }

    float sp[4] = {0, 0, 0, 0}, dp[4] = {0, 0, 0, 0};
    #pragma unroll
    for (int i = 0; i < 4; ++i) {
        int row = bm + ty * 4 + i;
        if (row < N) {
            __half2 p01 = __floats2half2_rn(acc[i][0], acc[i][1]);
            __half2 p23 = __floats2half2_rn(acc[i][2], acc[i][3]);
            uint2 pk;
            pk.x = *(unsigned int*)&p01;
            pk.y = *(unsigned int*)&p23;
            *(uint2*)(Hm + (size_t)row * C1 + bn + tx * 4) = pk;
            #pragma unroll
            for (int j = 0; j < 4; ++j) {
                int col = tx * 4 + j;
                float v = acc[i][j];
                sp[i] += v * as1[bn + col];
                dp[i] += v * ad1[bn + col];
            }
        }
    }
    #pragma unroll
    for (int off = 1; off < 16; off <<= 1) {
        #pragma unroll
        for (int i = 0; i < 4; ++i) {
            sp[i] += __shfl_xor(sp[i], off);
            dp[i] += __shfl_xor(dp[i], off);
        }
    }
    if (tx == 0) {
        #pragma unroll
        for (int i = 0; i < 4; ++i) {
            int row = bm + ty * 4 + i;
            if (row < N) {
                s1[row * H1N + head] = sp[i];
                d1[row * H1N + head] = dp[i];
            }
        }
    }
}

// ---------------- CSR build ----------------------------------------------
__global__ __launch_bounds__(256)
void hist_kernel(const int* __restrict__ ei, const int* __restrict__ flag,
                 int* __restrict__ counts, int E)
{
    int t = blockIdx.x * 256 + threadIdx.x;
    int stride = flag[0];
    if (t < E) atomicAdd(&counts[ei[(size_t)stride * (E + t)]], 1);
}

__global__ __launch_bounds__(1024)
void scan_kernel(const int* __restrict__ cnt, int* __restrict__ offs, int N)
{
    __shared__ int wsum[16];
    __shared__ int carry_s;
    const int t = threadIdx.x, lane = t & 63, w = t >> 6;
    if (t == 0) carry_s = 0;
    __syncthreads();
    for (int base = 0; base < N; base += 1024) {
        int idx = base + t;
        int v = (idx < N) ? cnt[idx] : 0;
        int incl = v;
        #pragma unroll
        for (int off = 1; off < 64; off <<= 1) {
            int u = __shfl_up(incl, off);
            if (lane >= off) incl += u;
        }
        if (lane == 63) wsum[w] = incl;
        __syncthreads();
        int wpre = 0;
        for (int i = 0; i < w; ++i) wpre += wsum[i];
        int c = carry_s;
        if (idx < N) offs[idx] = c + wpre + incl - v;
        __syncthreads();
        if (t == 1023) carry_s = c + wpre + incl;
        __syncthreads();
    }
    if (t == 0) offs[N] = carry_s;
}

__global__ __launch_bounds__(256)
void scatter_kernel(const int* __restrict__ ei, const int* __restrict__ flag,
                    const int* __restrict__ offs, int* __restrict__ fill,
                    int* __restrict__ ssrc, int E, int N)
{
    int t = blockIdx.x * 256 + threadIdx.x;
    if (t >= E + N) return;
    int stride = flag[0];
    int s, d;
    if (t < E) {
        s = ei[(size_t)stride * t];
        d = ei[(size_t)stride * (E + t)];
    } else {
        s = t - E; d = s;
    }
    int pos = offs[d] + atomicAdd(&fill[d], 1);
    ssrc[pos] = s;
}

// ---------------- layer-1 aggregate (v3) ----------------------------------
__global__ __launch_bounds__(256)
void agg1_kernel(const __half* __restrict__ Hm, const float* __restrict__ s1,
                 const float* __restrict__ d1, const int* __restrict__ offs,
                 const int* __restrict__ ssrc, const float* __restrict__ b1,
                 float* __restrict__ out1, int N)
{
    __shared__ float alpha[H1N][CAP];
    __shared__ int   srcs[CAP];
    __shared__ float invs[H1N];
    const int n    = blockIdx.x;
    const int t    = threadIdx.x;
    const int lane = t & 63;
    const int w    = t >> 6;
    const int beg  = offs[n], end = offs[n + 1];
    const int deg  = end - beg;
    const float dh = d1[n * H1N + w];

    if (deg <= CAP) {
        float mloc = -1e30f;
        for (int i = lane; i < deg; i += 64) {
            int s = ssrc[beg + i];
            if (w == 0) srcs[i] = s;
            float e = s1[s * H1N + w] + dh;
            e = e > 0.f ? e : 0.2f * e;
            alpha[w][i] = e;
            mloc = fmaxf(mloc, e);
        }
        #pragma unroll
        for (int off = 32; off; off >>= 1) mloc = fmaxf(mloc, __shfl_xor(mloc, off));
        float ssum = 0.f;
        for (int i = lane; i < deg; i += 64) {
            float ex = __expf(alpha[w][i] - mloc);
            alpha[w][i] = ex;
            ssum += ex;
        }
        #pragma unroll
        for (int off = 32; off; off >>= 1) ssum += __shfl_xor(ssum, off);
        if (lane == 0) invs[w] = 1.f / (ssum + 1e-16f);
        __syncthreads();

        float acc0 = 0.f, acc1 = 0.f, acc2 = 0.f, acc3 = 0.f;
        int i = 0;
        for (; i + 4 <= deg; i += 4) {
            int s0 = srcs[i],     s1i = srcs[i + 1];
            int s2 = srcs[i + 2], s3i = srcs[i + 3];
            float a0 = alpha[w][i],     a1 = alpha[w][i + 1];
            float a2 = alpha[w][i + 2], a3 = alpha[w][i + 3];
            float v0 = __half2float(Hm[(size_t)s0  * C1 + t]);
            float v1 = __half2float(Hm[(size_t)s1i * C1 + t]);
            float v2 = __half2float(Hm[(size_t)s2  * C1 + t]);
            float v3 = __half2float(Hm[(size_t)s3i * C1 + t]);
            acc0 += v0 * a0; acc1 += v1 * a1;
            acc2 += v2 * a2; acc3 += v3 * a3;
        }
        for (; i < deg; ++i)
            acc0 += __half2float(Hm[(size_t)srcs[i] * C1 + t]) * alpha[w][i];
        float acc = (acc0 + acc1) + (acc2 + acc3);
        out1[(size_t)n * C1 + t] = acc * invs[w] + b1[t];
        return;
    }

    float mloc = -1e30f;
    for (int p = beg + lane; p < end; p += 64) {
        float e = s1[ssrc[p] * H1N + w] + dh;
        e = e > 0.f ? e : 0.2f * e;
        mloc = fmaxf(mloc, e);
    }
    #pragma unroll
    for (int off = 32; off; off >>= 1) mloc = fmaxf(mloc, __shfl_xor(mloc, off));
    float ssum = 0.f;
    for (int p = beg + lane; p < end; p += 64) {
        float e = s1[ssrc[p] * H1N + w] + dh;
        e = e > 0.f ? e : 0.2f * e;
        ssum += __expf(e - mloc);
    }
    #pragma unroll
    for (int off = 32; off; off >>= 1) ssum += __shfl_xor(ssum, off);
    if (lane == 0) invs[w] = 1.f / (ssum + 1e-16f);

    float acc0 = 0.f, acc1 = 0.f, acc2 = 0.f, acc3 = 0.f;
    for (int c0 = 0; c0 < deg; c0 += CAP) {
        int cnt = min(CAP, deg - c0);
        for (int i = lane; i < cnt; i += 64) {
            int p = beg + c0 + i;
            int s = ssrc[p];
            if (w == 0) srcs[i] = s;
            float e = s1[s * H1N + w] + dh;
            e = e > 0.f ? e : 0.2f * e;
            alpha[w][i] = __expf(e - mloc);
        }
        __syncthreads();
        int i = 0;
        for (; i + 4 <= cnt; i += 4) {
            int s0 = srcs[i],     s1i = srcs[i + 1];
            int s2 = srcs[i + 2], s3i = srcs[i + 3];
            float a0 = alpha[w][i],     a1 = alpha[w][i + 1];
            float a2 = alpha[w][i + 2], a3 = alpha[w][i + 3];
            float v0 = __half2float(Hm[(size_t)s0  * C1 + t]);
            float v1 = __half2float(Hm[(size_t)s1i * C1 + t]);
            float v2 = __half2float(Hm[(size_t)s2  * C1 + t]);
            float v3 = __half2float(Hm[(size_t)s3i * C1 + t]);
            acc0 += v0 * a0; acc1 += v1 * a1;
            acc2 += v2 * a2; acc3 += v3 * a3;
        }
        for (; i < cnt; ++i)
            acc0 += __half2float(Hm[(size_t)srcs[i] * C1 + t]) * alpha[w][i];
        __syncthreads();
    }
    float acc = (acc0 + acc1) + (acc2 + acc3);
    out1[(size_t)n * C1 + t] = acc * invs[w] + b1[t];
}

// ---------------- BN column stats (1024 blocks: 4/CU for latency hiding) --
__global__ __launch_bounds__(256)
void bnstats_kernel(const float* __restrict__ out1, float* __restrict__ colsum,
                    float* __restrict__ colsq, int N)
{
    int t = threadIdx.x;
    float s = 0.f, q = 0.f;
    for (int r = blockIdx.x; r < N; r += gridDim.x) {
        float v = out1[(size_t)r * C1 + t];
        s += v; q += v * v;
    }
    atomicAdd(&colsum[t], s);
    atomicAdd(&colsq[t], q);
}

__global__ __launch_bounds__(256)
void bnfin_kernel(const float* __restrict__ colsum, const float* __restrict__ colsq,
                  const float* __restrict__ gamma, const float* __restrict__ beta,
                  float* __restrict__ scale, float* __restrict__ shift, int N)
{
    int t = threadIdx.x;
    float mu  = colsum[t] / (float)N;
    float var = colsq[t] / (float)N - mu * mu;
    float sc  = gamma[t] * rsqrtf(var + 1e-5f);
    scale[t] = sc;
    shift[t] = beta[t] - mu * sc;
}

// ---------------- GEMM2 (v2): 64 rows/block, thread=(row, jg:10 cols) -----
// No LDS atomics (s2/d2 via 4-lane shfl). W staged interleaved [k][jg*12]
// so float4/float2 reads are aligned; 10 FMA per 4 LDS insts, all
// broadcast/conflict-free. BN+ELU fused on A-stage.
__global__ __launch_bounds__(256)
void gemm2_kernel(const float* __restrict__ out1, const float* __restrict__ scale,
                  const float* __restrict__ shift, const float* __restrict__ W2,
                  const float* __restrict__ as2, const float* __restrict__ ad2,
                  float* __restrict__ h2, float* __restrict__ s2,
                  float* __restrict__ d2, int N)
{
    __shared__ float Asm[64][68];    // 64 rows x 64 k; stride 272B (16B-mult)
    __shared__ float Wsm[64 * 48];   // [k][jg][12]: jg*12 floats = 48B aligned
    const int t   = threadIdx.x;
    const int r   = t >> 2;          // 0..63
    const int jg  = t & 3;           // j0 = jg*10
    const int rb  = blockIdx.x * 64;
    const int row = rb + r;
    const int j0  = jg * 10;

    float acc[10] = {};

    for (int kc = 0; kc < C1; kc += 64) {
        // stage A (BN+ELU applied): 64 rows x 64 cols
        #pragma unroll
        for (int idx = t; idx < 64 * 16; idx += 256) {
            int ar = idx >> 4;
            int cg = (idx & 15) * 4;
            int arow = rb + ar;
            float4 v = make_float4(0.f, 0.f, 0.f, 0.f);
            if (arow < N) {
                v = *(const float4*)(out1 + (size_t)arow * C1 + kc + cg);
                float4 sc = *(const float4*)(scale + kc + cg);
                float4 sh = *(const float4*)(shift + kc + cg);
                v.x = v.x * sc.x + sh.x;
                v.y = v.y * sc.y + sh.y;
                v.z = v.z * sc.z + sh.z;
                v.w = v.w * sc.w + sh.w;
                v.x = v.x > 0.f ? v.x : (__expf(v.x) - 1.f);
                v.y = v.y > 0.f ? v.y : (__expf(v.y) - 1.f);
                v.z = v.z > 0.f ? v.z : (__expf(v.z) - 1.f);
                v.w = v.w > 0.f ? v.w : (__expf(v.w) - 1.f);
            }
            *(float4*)&Asm[ar][cg] = v;
        }
        // stage W interleaved: [k][j/10][j%10] with group stride 12
        #pragma unroll
        for (int idx = t; idx < 64 * 40; idx += 256) {
            int k = idx / 40, j = idx - k * 40;
            Wsm[k * 48 + (j / 10) * 12 + (j % 10)] = W2[(size_t)(kc + k) * NC + j];
        }
        __syncthreads();
        #pragma unroll 4
        for (int k = 0; k < 64; ++k) {
            float a = Asm[r][k];
            const float* wp = &Wsm[k * 48 + jg * 12];
            float4 w0 = *(const float4*)(wp);
            float4 w1 = *(const float4*)(wp + 4);
            float2 wv = *(const float2*)(wp + 8);
            acc[0] += a * w0.x; acc[1] += a * w0.y;
            acc[2] += a * w0.z; acc[3] += a * w0.w;
            acc[4] += a * w1.x; acc[5] += a * w1.y;
            acc[6] += a * w1.z; acc[7] += a * w1.w;
            acc[8] += a * wv.x; acc[9] += a * wv.y;
        }
        __syncthreads();
    }

    // epilogue: s2/d2 via 4-lane shfl (lanes 4r..4r+3 are consecutive)
    float sp = 0.f, dp = 0.f;
    #pragma unroll
    for (int jj = 0; jj < 10; ++jj) {
        sp += acc[jj] * as2[j0 + jj];
        dp += acc[jj] * ad2[j0 + jj];
    }
    sp += __shfl_xor(sp, 1); sp += __shfl_xor(sp, 2);
    dp += __shfl_xor(dp, 1); dp += __shfl_xor(dp, 2);
    if (row < N) {
        if (jg == 0) { s2[row] = sp; d2[row] = dp; }
        #pragma unroll
        for (int jj = 0; jj < 10; jj += 2)
            *(float2*)(h2 + (size_t)row * NC + j0 + jj) =
                make_float2(acc[jj], acc[jj + 1]);
    }
}

// ---------------- layer-2 aggregate (v2) + bias + log_softmax --------------
__global__ __launch_bounds__(256)
void agg2_kernel(const float* __restrict__ h2, const float* __restrict__ s2,
                 const float* __restrict__ d2, const int* __restrict__ offs,
                 const int* __restrict__ ssrc, const float* __restrict__ b2,
                 float* __restrict__ out, int N)
{
    __shared__ float al[4][CAP2];
    __shared__ int   sr[4][CAP2];
    int w = threadIdx.x >> 6;
    int node = blockIdx.x * 4 + w;
    if (node >= N) return;
    int lane = threadIdx.x & 63;
    int beg = offs[node], end = offs[node + 1];
    int deg = end - beg;
    float dn = d2[node];

    float v;
    if (deg <= CAP2) {
        float mloc = -1e30f;
        for (int i = lane; i < deg; i += 64) {
            int s = ssrc[beg + i];
            sr[w][i] = s;
            float e = s2[s] + dn;
            e = e > 0.f ? e : 0.2f * e;
            al[w][i] = e;
            mloc = fmaxf(mloc, e);
        }
        #pragma unroll
        for (int off = 32; off; off >>= 1) mloc = fmaxf(mloc, __shfl_xor(mloc, off));
        float ssum = 0.f;
        for (int i = lane; i < deg; i += 64) {
            float ex = __expf(al[w][i] - mloc);
            al[w][i] = ex;
            ssum += ex;
        }
        #pragma unroll
        for (int off = 32; off; off >>= 1) ssum += __shfl_xor(ssum, off);
        float inv = 1.f / (ssum + 1e-16f);

        int j = lane < NC ? lane : 0;
        float acc0 = 0.f, acc1 = 0.f, acc2 = 0.f, acc3 = 0.f;
        int i = 0;
        for (; i + 4 <= deg; i += 4) {
            float a0 = al[w][i],     a1 = al[w][i + 1];
            float a2 = al[w][i + 2], a3 = al[w][i + 3];
            acc0 += h2[(size_t)sr[w][i]     * NC + j] * a0;
            acc1 += h2[(size_t)sr[w][i + 1] * NC + j] * a1;
            acc2 += h2[(size_t)sr[w][i + 2] * NC + j] * a2;
            acc3 += h2[(size_t)sr[w][i + 3] * NC + j] * a3;
        }
        for (; i < deg; ++i)
            acc0 += h2[(size_t)sr[w][i] * NC + j] * al[w][i];
        v = ((acc0 + acc1) + (acc2 + acc3)) * inv + b2[j];
    } else {
        float m = -1e30f, denom = 0.f;
        for (int p = beg; p < end; ++p) {
            float e = s2[ssrc[p]] + dn;
            e = e > 0.f ? e : 0.2f * e;
            float mn = fmaxf(m, e);
            denom = denom * __expf(m - mn) + __expf(e - mn);
            m = mn;
        }
        float inv = 1.f / (denom + 1e-16f);
        int j = lane < NC ? lane : 0;
        float acc = 0.f;
        for (int p = beg; p < end; ++p) {
            int s = ssrc[p];
            float e = s2[s] + dn;
            e = e > 0.f ? e : 0.2f * e;
            acc += h2[(size_t)s * NC + j] * (__expf(e - m) * inv);
        }
        v = acc + b2[j];
    }

    float vm = lane < NC ? v : -1e30f;
    #pragma unroll
    for (int off = 32; off > 0; off >>= 1) vm = fmaxf(vm, __shfl_xor(vm, off));
    float ex = lane < NC ? __expf(v - vm) : 0.f;
    #pragma unroll
    for (int off = 32; off > 0; off >>= 1) ex += __shfl_xor(ex, off);
    if (lane < NC) out[(size_t)node * NC + lane] = v - vm - __logf(ex);
}

// ---------------- host ----------------------------------------------------
extern "C" void kernel_launch(void* const* d_in, const int* in_sizes, int n_in,
                              void* d_out, int out_size, void* d_ws, size_t ws_size,
                              hipStream_t stream)
{
    const float* x   = (const float*)d_in[0];
    const int*   ei  = (const int*)d_in[1];
    const float* W1  = (const float*)d_in[2];
    const float* as1 = (const float*)d_in[3];
    const float* ad1 = (const float*)d_in[4];
    const float* b1  = (const float*)d_in[5];
    const float* gm  = (const float*)d_in[6];
    const float* bt  = (const float*)d_in[7];
    const float* W2  = (const float*)d_in[8];
    const float* as2 = (const float*)d_in[9];
    const float* ad2 = (const float*)d_in[10];
    const float* b2  = (const float*)d_in[11];
    const int N = in_sizes[0] / FIN;
    const int E = in_sizes[1] / 2;

    char* p = (char*)d_ws;
    auto take = [&](size_t bytes) {
        char* r = p; p += (bytes + 255) & ~(size_t)255; return r;
    };
    __half* Hm    = (__half*)take((size_t)N * C1 * 2);
    float* out1   = (float*)take((size_t)N * C1 * 4);
    float* h2     = (float*)take((size_t)N * NC * 4);
    float* s1     = (float*)take((size_t)N * H1N * 4);
    float* d1     = (float*)take((size_t)N * H1N * 4);
    float* s2     = (float*)take((size_t)N * 4);
    float* d2v    = (float*)take((size_t)N * 4);
    float* colsum = (float*)take(C1 * 4);
    float* colsq  = (float*)take(C1 * 4);
    float* bnsc   = (float*)take(C1 * 4);
    float* bnsh   = (float*)take(C1 * 4);
    int*   counts = (int*)take((size_t)N * 4);
    int*   offs   = (int*)take((size_t)(N + 1) * 4);
    int*   fill   = (int*)take((size_t)N * 4);
    int*   ssrc   = (int*)take((size_t)(E + N) * 4);
    int*   eflag  = (int*)take(256);

    detect_kernel<<<1, 64, 0, stream>>>(ei, eflag, E);
    init_kernel<<<(N + 255) / 256, 256, 0, stream>>>(counts, fill, colsum, colsq, N);
    gemm1_kernel<<<dim3((N + 63) / 64, H1N), 256, 0, stream>>>(x, W1, as1, ad1, Hm, s1, d1, N);
    hist_kernel<<<(E + 255) / 256, 256, 0, stream>>>(ei, eflag, counts, E);
    scan_kernel<<<1, 1024, 0, stream>>>(counts, offs, N);
    scatter_kernel<<<(E + N + 255) / 256, 256, 0, stream>>>(ei, eflag, offs, fill, ssrc, E, N);
    agg1_kernel<<<N, 256, 0, stream>>>(Hm, s1, d1, offs, ssrc, b1, out1, N);
    bnstats_kernel<<<1024, 256, 0, stream>>>(out1, colsum, colsq, N);
    bnfin_kernel<<<1, 256, 0, stream>>>(colsum, colsq, gm, bt, bnsc, bnsh, N);
    gemm2_kernel<<<(N + 63) / 64, 256, 0, stream>>>(out1, bnsc, bnsh, W2, as2, ad2, h2, s2, d2v, N);
    agg2_kernel<<<(N + 3) / 4, 256, 0, stream>>>(h2, s2, d2v, offs, ssrc, b2, (float*)d_out, N);
}

// Round 12
// 483.451 us; speedup vs baseline: 1.5089x; 1.0240x over previous
//
#include <hip/hip_runtime.h>
#include <hip/hip_fp16.h>

constexpr int FIN = 256;   // input features
constexpr int C1  = 256;   // H1*hidden (layer-1 concat width)
constexpr int HID = 64;
constexpr int H1N = 4;
constexpr int NC  = 40;    // classes
constexpr int CAP = 256;   // agg1 LDS chunk (deg > CAP handled by fallback)
constexpr int CAP2 = 128;  // agg2 per-wave LDS capacity

using f16x8 = __attribute__((ext_vector_type(8))) _Float16;
using f32x4 = __attribute__((ext_vector_type(4))) float;

// ---------------- edge dtype detect: int32 vs int64 -----------------------
__global__ __launch_bounds__(64)
void detect_kernel(const int* __restrict__ ei, int* __restrict__ flag, int E)
{
    int lane = threadIdx.x;
    int q = lane * (E / 64);
    int v = ei[2 * q + 1];
    unsigned long long nz = __ballot(v != 0);
    if (lane == 0) flag[0] = (nz == 0ull) ? 2 : 1;
}

// ---------------- init ----------------------------------------------------
__global__ __launch_bounds__(256)
void init_kernel(int* __restrict__ counts, int* __restrict__ fill,
                 float* __restrict__ colsum, float* __restrict__ colsq, int N)
{
    int t = blockIdx.x * 256 + threadIdx.x;
    if (t < N) { counts[t] = 1; fill[t] = 0; }
    if (t < C1) { colsum[t] = 0.f; colsq[t] = 0.f; }
}

// ---------------- X -> fp16 (rows >= N zero-padded) ------------------------
__global__ __launch_bounds__(256)
void xcast_kernel(const float* __restrict__ X, _Float16* __restrict__ Xh,
                  int N, int NPAD)
{
    int idx = (blockIdx.x * 256 + threadIdx.x) * 4;
    if (idx >= NPAD * FIN) return;
    int row = idx >> 8;
    _Float16 h4[4];
    if (row < N) {
        float4 v = *(const float4*)(X + idx);
        h4[0] = (_Float16)v.x; h4[1] = (_Float16)v.y;
        h4[2] = (_Float16)v.z; h4[3] = (_Float16)v.w;
    } else {
        h4[0] = h4[1] = h4[2] = h4[3] = (_Float16)0.f;
    }
    *(uint2*)(Xh + idx) = *(uint2*)h4;
}

// ---------------- W1 -> fp16 transposed [col][k] ---------------------------
__global__ __launch_bounds__(256)
void w1cast_kernel(const float* __restrict__ W1, _Float16* __restrict__ W1t)
{
    __shared__ float tile[64][65];
    int bx = blockIdx.x & 3, by = blockIdx.x >> 2;
    int t = threadIdx.x;
    int c = t & 63, r4 = (t >> 6) * 16;
    #pragma unroll
    for (int i = 0; i < 16; ++i)
        tile[r4 + i][c] = W1[(size_t)(by * 64 + r4 + i) * C1 + bx * 64 + c];
    __syncthreads();
    #pragma unroll
    for (int i = 0; i < 16; ++i)
        W1t[(size_t)(bx * 64 + r4 + i) * FIN + by * 64 + c] =
            (_Float16)tile[c][r4 + i];
}

// ---------------- GEMM1 via fp16 MFMA, fused s1/d1 -------------------------
// Block = 64 rows x 256 cols (all 4 heads). Wave w: rows w*16..w*16+15.
// A frag: row = lane&15, k = ks*32 + (lane>>4)*8 + [0..7]  (16B global load)
// B frag: col = ct*16 + lane&15, same k (from transposed W1t, 16B load)
// C frag: col = ct*16 + lane&15, row = (lane>>4)*4 + reg   (m89-verified)
__global__ __launch_bounds__(256)
void gemm1_mfma_kernel(const _Float16* __restrict__ Xh,
                       const _Float16* __restrict__ W1t,
                       const float* __restrict__ as1, const float* __restrict__ ad1,
                       __half* __restrict__ Hm, float* __restrict__ s1,
                       float* __restrict__ d1, int N)
{
    const int t    = threadIdx.x;
    const int lane = t & 63;
    const int w    = t >> 6;
    const int rowbase = blockIdx.x * 64 + w * 16;
    const int lrow = lane & 15;
    const int kgrp = lane >> 4;
    const int arow = rowbase + lrow;          // A-load row (Xh is padded)

    f32x4 acc[16];
    #pragma unroll
    for (int i = 0; i < 16; ++i) acc[i] = f32x4{0.f, 0.f, 0.f, 0.f};

    #pragma unroll
    for (int ks = 0; ks < 8; ++ks) {
        f16x8 a = *(const f16x8*)(Xh + (size_t)arow * FIN + ks * 32 + kgrp * 8);
        #pragma unroll
        for (int ct = 0; ct < 16; ++ct) {
            f16x8 b = *(const f16x8*)(W1t + (size_t)(ct * 16 + lrow) * FIN
                                      + ks * 32 + kgrp * 8);
            acc[ct] = __builtin_amdgcn_mfma_f32_16x16x32_f16(a, b, acc[ct], 0, 0, 0);
        }
    }

    // epilogue: lane holds rows rowbase + kgrp*4 + reg, cols ct*16 + lrow
    #pragma unroll
    for (int reg = 0; reg < 4; ++reg) {
        int r = rowbase + kgrp * 4 + reg;
        bool ok = r < N;
        #pragma unroll
        for (int h = 0; h < 4; ++h) {
            float sp = 0.f, dp = 0.f;
            #pragma unroll
            for (int q = 0; q < 4; ++q) {
                int ct = h * 4 + q;
                float v = acc[ct][reg];
                sp += v * as1[ct * 16 + lrow];
                dp += v * ad1[ct * 16 + lrow];
            }
            sp += __shfl_xor(sp, 1); sp += __shfl_xor(sp, 2);
            sp += __shfl_xor(sp, 4); sp += __shfl_xor(sp, 8);
            dp += __shfl_xor(dp, 1); dp += __shfl_xor(dp, 2);
            dp += __shfl_xor(dp, 4); dp += __shfl_xor(dp, 8);
            if (ok && lrow == 0) {
                s1[r * H1N + h] = sp;
                d1[r * H1N + h] = dp;
            }
        }
        if (ok) {
            #pragma unroll
            for (int ct = 0; ct < 16; ++ct)
                Hm[(size_t)r * C1 + ct * 16 + lrow] = __float2half(acc[ct][reg]);
        }
    }
}

// ---------------- CSR build ----------------------------------------------
__global__ __launch_bounds__(256)
void hist_kernel(const int* __restrict__ ei, const int* __restrict__ flag,
                 int* __restrict__ counts, int E)
{
    int t = blockIdx.x * 256 + threadIdx.x;
    int stride = flag[0];
    if (t < E) atomicAdd(&counts[ei[(size_t)stride * (E + t)]], 1);
}

__global__ __launch_bounds__(1024)
void scan_kernel(const int* __restrict__ cnt, int* __restrict__ offs, int N)
{
    __shared__ int wsum[16];
    __shared__ int carry_s;
    const int t = threadIdx.x, lane = t & 63, w = t >> 6;
    if (t == 0) carry_s = 0;
    __syncthreads();
    for (int base = 0; base < N; base += 1024) {
        int idx = base + t;
        int v = (idx < N) ? cnt[idx] : 0;
        int incl = v;
        #pragma unroll
        for (int off = 1; off < 64; off <<= 1) {
            int u = __shfl_up(incl, off);
            if (lane >= off) incl += u;
        }
        if (lane == 63) wsum[w] = incl;
        __syncthreads();
        int wpre = 0;
        for (int i = 0; i < w; ++i) wpre += wsum[i];
        int c = carry_s;
        if (idx < N) offs[idx] = c + wpre + incl - v;
        __syncthreads();
        if (t == 1023) carry_s = c + wpre + incl;
        __syncthreads();
    }
    if (t == 0) offs[N] = carry_s;
}

__global__ __launch_bounds__(256)
void scatter_kernel(const int* __restrict__ ei, const int* __restrict__ flag,
                    const int* __restrict__ offs, int* __restrict__ fill,
                    int* __restrict__ ssrc, int E, int N)
{
    int t = blockIdx.x * 256 + threadIdx.x;
    if (t >= E + N) return;
    int stride = flag[0];
    int s, d;
    if (t < E) {
        s = ei[(size_t)stride * t];
        d = ei[(size_t)stride * (E + t)];
    } else {
        s = t - E; d = s;
    }
    int pos = offs[d] + atomicAdd(&fill[d], 1);
    ssrc[pos] = s;
}

// ---------------- layer-1 aggregate (v3) ----------------------------------
__global__ __launch_bounds__(256)
void agg1_kernel(const __half* __restrict__ Hm, const float* __restrict__ s1,
                 const float* __restrict__ d1, const int* __restrict__ offs,
                 const int* __restrict__ ssrc, const float* __restrict__ b1,
                 float* __restrict__ out1, int N)
{
    __shared__ float alpha[H1N][CAP];
    __shared__ int   srcs[CAP];
    __shared__ float invs[H1N];
    const int n    = blockIdx.x;
    const int t    = threadIdx.x;
    const int lane = t & 63;
    const int w    = t >> 6;
    const int beg  = offs[n], end = offs[n + 1];
    const int deg  = end - beg;
    const float dh = d1[n * H1N + w];

    if (deg <= CAP) {
        float mloc = -1e30f;
        for (int i = lane; i < deg; i += 64) {
            int s = ssrc[beg + i];
            if (w == 0) srcs[i] = s;
            float e = s1[s * H1N + w] + dh;
            e = e > 0.f ? e : 0.2f * e;
            alpha[w][i] = e;
            mloc = fmaxf(mloc, e);
        }
        #pragma unroll
        for (int off = 32; off; off >>= 1) mloc = fmaxf(mloc, __shfl_xor(mloc, off));
        float ssum = 0.f;
        for (int i = lane; i < deg; i += 64) {
            float ex = __expf(alpha[w][i] - mloc);
            alpha[w][i] = ex;
            ssum += ex;
        }
        #pragma unroll
        for (int off = 32; off; off >>= 1) ssum += __shfl_xor(ssum, off);
        if (lane == 0) invs[w] = 1.f / (ssum + 1e-16f);
        __syncthreads();

        float acc0 = 0.f, acc1 = 0.f, acc2 = 0.f, acc3 = 0.f;
        int i = 0;
        for (; i + 4 <= deg; i += 4) {
            int s0 = srcs[i],     s1i = srcs[i + 1];
            int s2 = srcs[i + 2], s3i = srcs[i + 3];
            float a0 = alpha[w][i],     a1 = alpha[w][i + 1];
            float a2 = alpha[w][i + 2], a3 = alpha[w][i + 3];
            float v0 = __half2float(Hm[(size_t)s0  * C1 + t]);
            float v1 = __half2float(Hm[(size_t)s1i * C1 + t]);
            float v2 = __half2float(Hm[(size_t)s2  * C1 + t]);
            float v3 = __half2float(Hm[(size_t)s3i * C1 + t]);
            acc0 += v0 * a0; acc1 += v1 * a1;
            acc2 += v2 * a2; acc3 += v3 * a3;
        }
        for (; i < deg; ++i)
            acc0 += __half2float(Hm[(size_t)srcs[i] * C1 + t]) * alpha[w][i];
        float acc = (acc0 + acc1) + (acc2 + acc3);
        out1[(size_t)n * C1 + t] = acc * invs[w] + b1[t];
        return;
    }

    float mloc = -1e30f;
    for (int p = beg + lane; p < end; p += 64) {
        float e = s1[ssrc[p] * H1N + w] + dh;
        e = e > 0.f ? e : 0.2f * e;
        mloc = fmaxf(mloc, e);
    }
    #pragma unroll
    for (int off = 32; off; off >>= 1) mloc = fmaxf(mloc, __shfl_xor(mloc, off));
    float ssum = 0.f;
    for (int p = beg + lane; p < end; p += 64) {
        float e = s1[ssrc[p] * H1N + w] + dh;
        e = e > 0.f ? e : 0.2f * e;
        ssum += __expf(e - mloc);
    }
    #pragma unroll
    for (int off = 32; off; off >>= 1) ssum += __shfl_xor(ssum, off);
    if (lane == 0) invs[w] = 1.f / (ssum + 1e-16f);

    float acc0 = 0.f, acc1 = 0.f, acc2 = 0.f, acc3 = 0.f;
    for (int c0 = 0; c0 < deg; c0 += CAP) {
        int cnt = min(CAP, deg - c0);
        for (int i = lane; i < cnt; i += 64) {
            int p = beg + c0 + i;
            int s = ssrc[p];
            if (w == 0) srcs[i] = s;
            float e = s1[s * H1N + w] + dh;
            e = e > 0.f ? e : 0.2f * e;
            alpha[w][i] = __expf(e - mloc);
        }
        __syncthreads();
        int i = 0;
        for (; i + 4 <= cnt; i += 4) {
            int s0 = srcs[i],     s1i = srcs[i + 1];
            int s2 = srcs[i + 2], s3i = srcs[i + 3];
            float a0 = alpha[w][i],     a1 = alpha[w][i + 1];
            float a2 = alpha[w][i + 2], a3 = alpha[w][i + 3];
            float v0 = __half2float(Hm[(size_t)s0  * C1 + t]);
            float v1 = __half2float(Hm[(size_t)s1i * C1 + t]);
            float v2 = __half2float(Hm[(size_t)s2  * C1 + t]);
            float v3 = __half2float(Hm[(size_t)s3i * C1 + t]);
            acc0 += v0 * a0; acc1 += v1 * a1;
            acc2 += v2 * a2; acc3 += v3 * a3;
        }
        for (; i < cnt; ++i)
            acc0 += __half2float(Hm[(size_t)srcs[i] * C1 + t]) * alpha[w][i];
        __syncthreads();
    }
    float acc = (acc0 + acc1) + (acc2 + acc3);
    out1[(size_t)n * C1 + t] = acc * invs[w] + b1[t];
}

// ---------------- BN column stats (1024 blocks: 4/CU) ----------------------
__global__ __launch_bounds__(256)
void bnstats_kernel(const float* __restrict__ out1, float* __restrict__ colsum,
                    float* __restrict__ colsq, int N)
{
    int t = threadIdx.x;
    float s = 0.f, q = 0.f;
    for (int r = blockIdx.x; r < N; r += gridDim.x) {
        float v = out1[(size_t)r * C1 + t];
        s += v; q += v * v;
    }
    atomicAdd(&colsum[t], s);
    atomicAdd(&colsq[t], q);
}

__global__ __launch_bounds__(256)
void bnfin_kernel(const float* __restrict__ colsum, const float* __restrict__ colsq,
                  const float* __restrict__ gamma, const float* __restrict__ beta,
                  float* __restrict__ scale, float* __restrict__ shift, int N)
{
    int t = threadIdx.x;
    float mu  = colsum[t] / (float)N;
    float var = colsq[t] / (float)N - mu * mu;
    float sc  = gamma[t] * rsqrtf(var + 1e-5f);
    scale[t] = sc;
    shift[t] = beta[t] - mu * sc;
}

// ---------------- GEMM2 (v2): 64 rows/block, thread=(row, jg:10 cols) -----
__global__ __launch_bounds__(256)
void gemm2_kernel(const float* __restrict__ out1, const float* __restrict__ scale,
                  const float* __restrict__ shift, const float* __restrict__ W2,
                  const float* __restrict__ as2, const float* __restrict__ ad2,
                  float* __restrict__ h2, float* __restrict__ s2,
                  float* __restrict__ d2, int N)
{
    __shared__ float Asm[64][68];
    __shared__ float Wsm[64 * 48];
    const int t   = threadIdx.x;
    const int r   = t >> 2;
    const int jg  = t & 3;
    const int rb  = blockIdx.x * 64;
    const int row = rb + r;
    const int j0  = jg * 10;

    float acc[10] = {};

    for (int kc = 0; kc < C1; kc += 64) {
        #pragma unroll
        for (int idx = t; idx < 64 * 16; idx += 256) {
            int ar = idx >> 4;
            int cg = (idx & 15) * 4;
            int arow = rb + ar;
            float4 v = make_float4(0.f, 0.f, 0.f, 0.f);
            if (arow < N) {
                v = *(const float4*)(out1 + (size_t)arow * C1 + kc + cg);
                float4 sc = *(const float4*)(scale + kc + cg);
                float4 sh = *(const float4*)(shift + kc + cg);
                v.x = v.x * sc.x + sh.x;
                v.y = v.y * sc.y + sh.y;
                v.z = v.z * sc.z + sh.z;
                v.w = v.w * sc.w + sh.w;
                v.x = v.x > 0.f ? v.x : (__expf(v.x) - 1.f);
                v.y = v.y > 0.f ? v.y : (__expf(v.y) - 1.f);
                v.z = v.z > 0.f ? v.z : (__expf(v.z) - 1.f);
                v.w = v.w > 0.f ? v.w : (__expf(v.w) - 1.f);
            }
            *(float4*)&Asm[ar][cg] = v;
        }
        #pragma unroll
        for (int idx = t; idx < 64 * 40; idx += 256) {
            int k = idx / 40, j = idx - k * 40;
            Wsm[k * 48 + (j / 10) * 12 + (j % 10)] = W2[(size_t)(kc + k) * NC + j];
        }
        __syncthreads();
        #pragma unroll 4
        for (int k = 0; k < 64; ++k) {
            float a = Asm[r][k];
            const float* wp = &Wsm[k * 48 + jg * 12];
            float4 w0 = *(const float4*)(wp);
            float4 w1 = *(const float4*)(wp + 4);
            float2 wv = *(const float2*)(wp + 8);
            acc[0] += a * w0.x; acc[1] += a * w0.y;
            acc[2] += a * w0.z; acc[3] += a * w0.w;
            acc[4] += a * w1.x; acc[5] += a * w1.y;
            acc[6] += a * w1.z; acc[7] += a * w1.w;
            acc[8] += a * wv.x; acc[9] += a * wv.y;
        }
        __syncthreads();
    }

    float sp = 0.f, dp = 0.f;
    #pragma unroll
    for (int jj = 0; jj < 10; ++jj) {
        sp += acc[jj] * as2[j0 + jj];
        dp += acc[jj] * ad2[j0 + jj];
    }
    sp += __shfl_xor(sp, 1); sp += __shfl_xor(sp, 2);
    dp += __shfl_xor(dp, 1); dp += __shfl_xor(dp, 2);
    if (row < N) {
        if (jg == 0) { s2[row] = sp; d2[row] = dp; }
        #pragma unroll
        for (int jj = 0; jj < 10; jj += 2)
            *(float2*)(h2 + (size_t)row * NC + j0 + jj) =
                make_float2(acc[jj], acc[jj + 1]);
    }
}

// ---------------- layer-2 aggregate (v2) + bias + log_softmax --------------
__global__ __launch_bounds__(256)
void agg2_kernel(const float* __restrict__ h2, const float* __restrict__ s2,
                 const float* __restrict__ d2, const int* __restrict__ offs,
                 const int* __restrict__ ssrc, const float* __restrict__ b2,
                 float* __restrict__ out, int N)
{
    __shared__ float al[4][CAP2];
    __shared__ int   sr[4][CAP2];
    int w = threadIdx.x >> 6;
    int node = blockIdx.x * 4 + w;
    if (node >= N) return;
    int lane = threadIdx.x & 63;
    int beg = offs[node], end = offs[node + 1];
    int deg = end - beg;
    float dn = d2[node];

    float v;
    if (deg <= CAP2) {
        float mloc = -1e30f;
        for (int i = lane; i < deg; i += 64) {
            int s = ssrc[beg + i];
            sr[w][i] = s;
            float e = s2[s] + dn;
            e = e > 0.f ? e : 0.2f * e;
            al[w][i] = e;
            mloc = fmaxf(mloc, e);
        }
        #pragma unroll
        for (int off = 32; off; off >>= 1) mloc = fmaxf(mloc, __shfl_xor(mloc, off));
        float ssum = 0.f;
        for (int i = lane; i < deg; i += 64) {
            float ex = __expf(al[w][i] - mloc);
            al[w][i] = ex;
            ssum += ex;
        }
        #pragma unroll
        for (int off = 32; off; off >>= 1) ssum += __shfl_xor(ssum, off);
        float inv = 1.f / (ssum + 1e-16f);

        int j = lane < NC ? lane : 0;
        float acc0 = 0.f, acc1 = 0.f, acc2 = 0.f, acc3 = 0.f;
        int i = 0;
        for (; i + 4 <= deg; i += 4) {
            float a0 = al[w][i],     a1 = al[w][i + 1];
            float a2 = al[w][i + 2], a3 = al[w][i + 3];
            acc0 += h2[(size_t)sr[w][i]     * NC + j] * a0;
            acc1 += h2[(size_t)sr[w][i + 1] * NC + j] * a1;
            acc2 += h2[(size_t)sr[w][i + 2] * NC + j] * a2;
            acc3 += h2[(size_t)sr[w][i + 3] * NC + j] * a3;
        }
        for (; i < deg; ++i)
            acc0 += h2[(size_t)sr[w][i] * NC + j] * al[w][i];
        v = ((acc0 + acc1) + (acc2 + acc3)) * inv + b2[j];
    } else {
        float m = -1e30f, denom = 0.f;
        for (int p = beg; p < end; ++p) {
            float e = s2[ssrc[p]] + dn;
            e = e > 0.f ? e : 0.2f * e;
            float mn = fmaxf(m, e);
            denom = denom * __expf(m - mn) + __expf(e - mn);
            m = mn;
        }
        float inv = 1.f / (denom + 1e-16f);
        int j = lane < NC ? lane : 0;
        float acc = 0.f;
        for (int p = beg; p < end; ++p) {
            int s = ssrc[p];
            float e = s2[s] + dn;
            e = e > 0.f ? e : 0.2f * e;
            acc += h2[(size_t)s * NC + j] * (__expf(e - m) * inv);
        }
        v = acc + b2[j];
    }

    float vm = lane < NC ? v : -1e30f;
    #pragma unroll
    for (int off = 32; off > 0; off >>= 1) vm = fmaxf(vm, __shfl_xor(vm, off));
    float ex = lane < NC ? __expf(v - vm) : 0.f;
    #pragma unroll
    for (int off = 32; off > 0; off >>= 1) ex += __shfl_xor(ex, off);
    if (lane < NC) out[(size_t)node * NC + lane] = v - vm - __logf(ex);
}

// ---------------- host ----------------------------------------------------
extern "C" void kernel_launch(void* const* d_in, const int* in_sizes, int n_in,
                              void* d_out, int out_size, void* d_ws, size_t ws_size,
                              hipStream_t stream)
{
    const float* x   = (const float*)d_in[0];
    const int*   ei  = (const int*)d_in[1];
    const float* W1  = (const float*)d_in[2];
    const float* as1 = (const float*)d_in[3];
    const float* ad1 = (const float*)d_in[4];
    const float* b1  = (const float*)d_in[5];
    const float* gm  = (const float*)d_in[6];
    const float* bt  = (const float*)d_in[7];
    const float* W2  = (const float*)d_in[8];
    const float* as2 = (const float*)d_in[9];
    const float* ad2 = (const float*)d_in[10];
    const float* b2  = (const float*)d_in[11];
    const int N = in_sizes[0] / FIN;
    const int E = in_sizes[1] / 2;
    const int NPAD = (N + 63) & ~63;

    char* p = (char*)d_ws;
    auto take = [&](size_t bytes) {
        char* r = p; p += (bytes + 255) & ~(size_t)255; return r;
    };
    __half* Hm       = (__half*)take((size_t)N * C1 * 2);
    _Float16* Xh     = (_Float16*)take((size_t)NPAD * FIN * 2);
    _Float16* W1t    = (_Float16*)take((size_t)FIN * C1 * 2);
    float* out1   = (float*)take((size_t)N * C1 * 4);
    float* h2     = (float*)take((size_t)N * NC * 4);
    float* s1     = (float*)take((size_t)N * H1N * 4);
    float* d1     = (float*)take((size_t)N * H1N * 4);
    float* s2     = (float*)take((size_t)N * 4);
    float* d2v    = (float*)take((size_t)N * 4);
    float* colsum = (float*)take(C1 * 4);
    float* colsq  = (float*)take(C1 * 4);
    float* bnsc   = (float*)take(C1 * 4);
    float* bnsh   = (float*)take(C1 * 4);
    int*   counts = (int*)take((size_t)N * 4);
    int*   offs   = (int*)take((size_t)(N + 1) * 4);
    int*   fill   = (int*)take((size_t)N * 4);
    int*   ssrc   = (int*)take((size_t)(E + N) * 4);
    int*   eflag  = (int*)take(256);

    detect_kernel<<<1, 64, 0, stream>>>(ei, eflag, E);
    init_kernel<<<(N + 255) / 256, 256, 0, stream>>>(counts, fill, colsum, colsq, N);
    xcast_kernel<<<(NPAD * FIN / 4 + 255) / 256, 256, 0, stream>>>(x, Xh, N, NPAD);
    w1cast_kernel<<<16, 256, 0, stream>>>(W1, W1t);
    gemm1_mfma_kernel<<<NPAD / 64, 256, 0, stream>>>(Xh, W1t, as1, ad1, Hm, s1, d1, N);
    hist_kernel<<<(E + 255) / 256, 256, 0, stream>>>(ei, eflag, counts, E);
    scan_kernel<<<1, 1024, 0, stream>>>(counts, offs, N);
    scatter_kernel<<<(E + N + 255) / 256, 256, 0, stream>>>(ei, eflag, offs, fill, ssrc, E, N);
    agg1_kernel<<<N, 256, 0, stream>>>(Hm, s1, d1, offs, ssrc, b1, out1, N);
    bnstats_kernel<<<1024, 256, 0, stream>>>(out1, colsum, colsq, N);
    bnfin_kernel<<<1, 256, 0, stream>>>(colsum, colsq, gm, bt, bnsc, bnsh, N);
    gemm2_kernel<<<(N + 63) / 64, 256, 0, stream>>>(out1, bnsc, bnsh, W2, as2, ad2, h2, s2, d2v, N);
    agg2_kernel<<<(N + 3) / 4, 256, 0, stream>>>(h2, s2, d2v, offs, ssrc, b2, (float*)d_out, N);
}

// Round 13
// 475.018 us; speedup vs baseline: 1.5356x; 1.0178x over previous
//
#include <hip/hip_runtime.h>
#include <hip/hip_fp16.h>

constexpr int FIN = 256;   // input features
constexpr int C1  = 256;   // H1*hidden (layer-1 concat width)
constexpr int HID = 64;
constexpr int H1N = 4;
constexpr int NC  = 40;    // classes
constexpr int CAP = 256;   // agg1 LDS chunk (deg > CAP handled by fallback)
constexpr int CAP2 = 128;  // agg2 per-wave LDS capacity

using f16x8 = __attribute__((ext_vector_type(8))) _Float16;
using f32x4 = __attribute__((ext_vector_type(4))) float;

// ---------------- edge dtype detect: int32 vs int64 -----------------------
__global__ __launch_bounds__(64)
void detect_kernel(const int* __restrict__ ei, int* __restrict__ flag, int E)
{
    int lane = threadIdx.x;
    int q = lane * (E / 64);
    int v = ei[2 * q + 1];
    unsigned long long nz = __ballot(v != 0);
    if (lane == 0) flag[0] = (nz == 0ull) ? 2 : 1;
}

// ---------------- init ----------------------------------------------------
__global__ __launch_bounds__(256)
void init_kernel(int* __restrict__ counts, int* __restrict__ fill,
                 float* __restrict__ colsum, float* __restrict__ colsq, int N)
{
    int t = blockIdx.x * 256 + threadIdx.x;
    if (t < N) { counts[t] = 1; fill[t] = 0; }
    if (t < C1) { colsum[t] = 0.f; colsq[t] = 0.f; }
}

// ---------------- X -> fp16 (rows >= N zero-padded) ------------------------
__global__ __launch_bounds__(256)
void xcast_kernel(const float* __restrict__ X, _Float16* __restrict__ Xh,
                  int N, int NPAD)
{
    int idx = (blockIdx.x * 256 + threadIdx.x) * 4;
    if (idx >= NPAD * FIN) return;
    int row = idx >> 8;
    _Float16 h4[4];
    if (row < N) {
        float4 v = *(const float4*)(X + idx);
        h4[0] = (_Float16)v.x; h4[1] = (_Float16)v.y;
        h4[2] = (_Float16)v.z; h4[3] = (_Float16)v.w;
    } else {
        h4[0] = h4[1] = h4[2] = h4[3] = (_Float16)0.f;
    }
    *(uint2*)(Xh + idx) = *(uint2*)h4;
}

// ---------------- W1 -> fp16 transposed [col][k] ---------------------------
__global__ __launch_bounds__(256)
void w1cast_kernel(const float* __restrict__ W1, _Float16* __restrict__ W1t)
{
    __shared__ float tile[64][65];
    int bx = blockIdx.x & 3, by = blockIdx.x >> 2;
    int t = threadIdx.x;
    int c = t & 63, r4 = (t >> 6) * 16;
    #pragma unroll
    for (int i = 0; i < 16; ++i)
        tile[r4 + i][c] = W1[(size_t)(by * 64 + r4 + i) * C1 + bx * 64 + c];
    __syncthreads();
    #pragma unroll
    for (int i = 0; i < 16; ++i)
        W1t[(size_t)(bx * 64 + r4 + i) * FIN + by * 64 + c] =
            (_Float16)tile[c][r4 + i];
}

// ---------------- GEMM1 via fp16 MFMA, fused s1/d1 -------------------------
__global__ __launch_bounds__(256)
void gemm1_mfma_kernel(const _Float16* __restrict__ Xh,
                       const _Float16* __restrict__ W1t,
                       const float* __restrict__ as1, const float* __restrict__ ad1,
                       __half* __restrict__ Hm, float* __restrict__ s1,
                       float* __restrict__ d1, int N)
{
    const int t    = threadIdx.x;
    const int lane = t & 63;
    const int w    = t >> 6;
    const int rowbase = blockIdx.x * 64 + w * 16;
    const int lrow = lane & 15;
    const int kgrp = lane >> 4;
    const int arow = rowbase + lrow;          // A-load row (Xh is padded)

    f32x4 acc[16];
    #pragma unroll
    for (int i = 0; i < 16; ++i) acc[i] = f32x4{0.f, 0.f, 0.f, 0.f};

    #pragma unroll
    for (int ks = 0; ks < 8; ++ks) {
        f16x8 a = *(const f16x8*)(Xh + (size_t)arow * FIN + ks * 32 + kgrp * 8);
        #pragma unroll
        for (int ct = 0; ct < 16; ++ct) {
            f16x8 b = *(const f16x8*)(W1t + (size_t)(ct * 16 + lrow) * FIN
                                      + ks * 32 + kgrp * 8);
            acc[ct] = __builtin_amdgcn_mfma_f32_16x16x32_f16(a, b, acc[ct], 0, 0, 0);
        }
    }

    // epilogue: lane holds rows rowbase + kgrp*4 + reg, cols ct*16 + lrow
    #pragma unroll
    for (int reg = 0; reg < 4; ++reg) {
        int r = rowbase + kgrp * 4 + reg;
        bool ok = r < N;
        #pragma unroll
        for (int h = 0; h < 4; ++h) {
            float sp = 0.f, dp = 0.f;
            #pragma unroll
            for (int q = 0; q < 4; ++q) {
                int ct = h * 4 + q;
                float v = acc[ct][reg];
                sp += v * as1[ct * 16 + lrow];
                dp += v * ad1[ct * 16 + lrow];
            }
            sp += __shfl_xor(sp, 1); sp += __shfl_xor(sp, 2);
            sp += __shfl_xor(sp, 4); sp += __shfl_xor(sp, 8);
            dp += __shfl_xor(dp, 1); dp += __shfl_xor(dp, 2);
            dp += __shfl_xor(dp, 4); dp += __shfl_xor(dp, 8);
            if (ok && lrow == 0) {
                s1[r * H1N + h] = sp;
                d1[r * H1N + h] = dp;
            }
        }
        if (ok) {
            #pragma unroll
            for (int ct = 0; ct < 16; ++ct)
                Hm[(size_t)r * C1 + ct * 16 + lrow] = __float2half(acc[ct][reg]);
        }
    }
}

// ---------------- CSR build ----------------------------------------------
__global__ __launch_bounds__(256)
void hist_kernel(const int* __restrict__ ei, const int* __restrict__ flag,
                 int* __restrict__ counts, int E)
{
    int t = blockIdx.x * 256 + threadIdx.x;
    int stride = flag[0];
    if (t < E) atomicAdd(&counts[ei[(size_t)stride * (E + t)]], 1);
}

__global__ __launch_bounds__(1024)
void scan_kernel(const int* __restrict__ cnt, int* __restrict__ offs, int N)
{
    __shared__ int wsum[16];
    __shared__ int carry_s;
    const int t = threadIdx.x, lane = t & 63, w = t >> 6;
    if (t == 0) carry_s = 0;
    __syncthreads();
    for (int base = 0; base < N; base += 1024) {
        int idx = base + t;
        int v = (idx < N) ? cnt[idx] : 0;
        int incl = v;
        #pragma unroll
        for (int off = 1; off < 64; off <<= 1) {
            int u = __shfl_up(incl, off);
            if (lane >= off) incl += u;
        }
        if (lane == 63) wsum[w] = incl;
        __syncthreads();
        int wpre = 0;
        for (int i = 0; i < w; ++i) wpre += wsum[i];
        int c = carry_s;
        if (idx < N) offs[idx] = c + wpre + incl - v;
        __syncthreads();
        if (t == 1023) carry_s = c + wpre + incl;
        __syncthreads();
    }
    if (t == 0) offs[N] = carry_s;
}

__global__ __launch_bounds__(256)
void scatter_kernel(const int* __restrict__ ei, const int* __restrict__ flag,
                    const int* __restrict__ offs, int* __restrict__ fill,
                    int* __restrict__ ssrc, int E, int N)
{
    int t = blockIdx.x * 256 + threadIdx.x;
    if (t >= E + N) return;
    int stride = flag[0];
    int s, d;
    if (t < E) {
        s = ei[(size_t)stride * t];
        d = ei[(size_t)stride * (E + t)];
    } else {
        s = t - E; d = s;
    }
    int pos = offs[d] + atomicAdd(&fill[d], 1);
    ssrc[pos] = s;
}

// ---------------- layer-1 aggregate (v4): half2 gather ---------------------
// Stats: wave w = head w (unchanged, verified). Gather: 2 groups x 128
// threads; group g takes edges i%2==g; thread covers channel pair (2l,2l+1)
// via one 4B half2 load (256B/wave-instr vs 128B before, half the addr
// calc). Group partials combined in LDS.
__global__ __launch_bounds__(256)
void agg1_kernel(const __half* __restrict__ Hm, const float* __restrict__ s1,
                 const float* __restrict__ d1, const int* __restrict__ offs,
                 const int* __restrict__ ssrc, const float* __restrict__ b1,
                 float* __restrict__ out1, int N)
{
    __shared__ float alpha[H1N][CAP];
    __shared__ int   srcs[CAP];
    __shared__ float invs[H1N];
    __shared__ float part[C1];
    const int n    = blockIdx.x;
    const int t    = threadIdx.x;
    const int lane = t & 63;
    const int w    = t >> 6;
    const int beg  = offs[n], end = offs[n + 1];
    const int deg  = end - beg;
    const float dh = d1[n * H1N + w];

    if (deg <= CAP) {
        // ---- stats (wave-parallel, e staged once) ----
        float mloc = -1e30f;
        for (int i = lane; i < deg; i += 64) {
            int s = ssrc[beg + i];
            if (w == 0) srcs[i] = s;
            float e = s1[s * H1N + w] + dh;
            e = e > 0.f ? e : 0.2f * e;   // leaky_relu 0.2
            alpha[w][i] = e;
            mloc = fmaxf(mloc, e);
        }
        #pragma unroll
        for (int off = 32; off; off >>= 1) mloc = fmaxf(mloc, __shfl_xor(mloc, off));
        float ssum = 0.f;
        for (int i = lane; i < deg; i += 64) {
            float ex = __expf(alpha[w][i] - mloc);
            alpha[w][i] = ex;
            ssum += ex;
        }
        #pragma unroll
        for (int off = 32; off; off >>= 1) ssum += __shfl_xor(ssum, off);
        if (lane == 0) invs[w] = 1.f / (ssum + 1e-16f);
        __syncthreads();

        // ---- gather: half2 per thread, 2 edge-groups ----
        const int g = t >> 7;          // edge parity group
        const int l = t & 127;         // lane-in-group
        const int c = 2 * l;           // channel pair
        const int h = l >> 5;          // head of this channel pair
        float ax = 0.f, ay = 0.f, bx = 0.f, by = 0.f;
        int i = g;
        for (; i + 2 < deg; i += 4) {  // 2 edges/iter for this group
            int s0 = srcs[i], s1i = srcs[i + 2];
            float a0 = alpha[h][i], a1 = alpha[h][i + 2];
            __half2 u0 = *(const __half2*)(Hm + (size_t)s0  * C1 + c);
            __half2 u1 = *(const __half2*)(Hm + (size_t)s1i * C1 + c);
            float2 v0 = __half22float2(u0);
            float2 v1 = __half22float2(u1);
            ax += v0.x * a0; ay += v0.y * a0;
            bx += v1.x * a1; by += v1.y * a1;
        }
        for (; i < deg; i += 2) {
            int s0 = srcs[i];
            float a0 = alpha[h][i];
            __half2 u0 = *(const __half2*)(Hm + (size_t)s0 * C1 + c);
            float2 v0 = __half22float2(u0);
            ax += v0.x * a0; ay += v0.y * a0;
        }
        ax += bx; ay += by;
        if (g == 1) *(float2*)&part[c] = make_float2(ax, ay);
        __syncthreads();
        if (g == 0) {
            float inv = invs[h];
            float2 pr = *(const float2*)&part[c];
            float2 r;
            r.x = (ax + pr.x) * inv + b1[c];
            r.y = (ay + pr.y) * inv + b1[c + 1];
            *(float2*)(out1 + (size_t)n * C1 + c) = r;
        }
        return;
    }

    // ---- fallback: deg > CAP (3-pass, chunked, per-channel thread) ----
    float mloc = -1e30f;
    for (int p = beg + lane; p < end; p += 64) {
        float e = s1[ssrc[p] * H1N + w] + dh;
        e = e > 0.f ? e : 0.2f * e;
        mloc = fmaxf(mloc, e);
    }
    #pragma unroll
    for (int off = 32; off; off >>= 1) mloc = fmaxf(mloc, __shfl_xor(mloc, off));
    float ssum = 0.f;
    for (int p = beg + lane; p < end; p += 64) {
        float e = s1[ssrc[p] * H1N + w] + dh;
        e = e > 0.f ? e : 0.2f * e;
        ssum += __expf(e - mloc);
    }
    #pragma unroll
    for (int off = 32; off; off >>= 1) ssum += __shfl_xor(ssum, off);
    if (lane == 0) invs[w] = 1.f / (ssum + 1e-16f);

    float acc0 = 0.f, acc1 = 0.f, acc2 = 0.f, acc3 = 0.f;
    for (int c0 = 0; c0 < deg; c0 += CAP) {
        int cnt = min(CAP, deg - c0);
        for (int i = lane; i < cnt; i += 64) {
            int p = beg + c0 + i;
            int s = ssrc[p];
            if (w == 0) srcs[i] = s;
            float e = s1[s * H1N + w] + dh;
            e = e > 0.f ? e : 0.2f * e;
            alpha[w][i] = __expf(e - mloc);
        }
        __syncthreads();
        int i = 0;
        for (; i + 4 <= cnt; i += 4) {
            int s0 = srcs[i],     s1i = srcs[i + 1];
            int s2 = srcs[i + 2], s3i = srcs[i + 3];
            float a0 = alpha[w][i],     a1 = alpha[w][i + 1];
            float a2 = alpha[w][i + 2], a3 = alpha[w][i + 3];
            float v0 = __half2float(Hm[(size_t)s0  * C1 + t]);
            float v1 = __half2float(Hm[(size_t)s1i * C1 + t]);
            float v2 = __half2float(Hm[(size_t)s2  * C1 + t]);
            float v3 = __half2float(Hm[(size_t)s3i * C1 + t]);
            acc0 += v0 * a0; acc1 += v1 * a1;
            acc2 += v2 * a2; acc3 += v3 * a3;
        }
        for (; i < cnt; ++i)
            acc0 += __half2float(Hm[(size_t)srcs[i] * C1 + t]) * alpha[w][i];
        __syncthreads();
    }
    float acc = (acc0 + acc1) + (acc2 + acc3);
    out1[(size_t)n * C1 + t] = acc * invs[w] + b1[t];
}

// ---------------- BN column stats (1024 blocks: 4/CU) ----------------------
__global__ __launch_bounds__(256)
void bnstats_kernel(const float* __restrict__ out1, float* __restrict__ colsum,
                    float* __restrict__ colsq, int N)
{
    int t = threadIdx.x;
    float s = 0.f, q = 0.f;
    for (int r = blockIdx.x; r < N; r += gridDim.x) {
        float v = out1[(size_t)r * C1 + t];
        s += v; q += v * v;
    }
    atomicAdd(&colsum[t], s);
    atomicAdd(&colsq[t], q);
}

__global__ __launch_bounds__(256)
void bnfin_kernel(const float* __restrict__ colsum, const float* __restrict__ colsq,
                  const float* __restrict__ gamma, const float* __restrict__ beta,
                  float* __restrict__ scale, float* __restrict__ shift, int N)
{
    int t = threadIdx.x;
    float mu  = colsum[t] / (float)N;
    float var = colsq[t] / (float)N - mu * mu;
    float sc  = gamma[t] * rsqrtf(var + 1e-5f);
    scale[t] = sc;
    shift[t] = beta[t] - mu * sc;
}

// ---------------- GEMM2 (v2): 64 rows/block, thread=(row, jg:10 cols) -----
__global__ __launch_bounds__(256)
void gemm2_kernel(const float* __restrict__ out1, const float* __restrict__ scale,
                  const float* __restrict__ shift, const float* __restrict__ W2,
                  const float* __restrict__ as2, const float* __restrict__ ad2,
                  float* __restrict__ h2, float* __restrict__ s2,
                  float* __restrict__ d2, int N)
{
    __shared__ float Asm[64][68];
    __shared__ float Wsm[64 * 48];
    const int t   = threadIdx.x;
    const int r   = t >> 2;
    const int jg  = t & 3;
    const int rb  = blockIdx.x * 64;
    const int row = rb + r;
    const int j0  = jg * 10;

    float acc[10] = {};

    for (int kc = 0; kc < C1; kc += 64) {
        #pragma unroll
        for (int idx = t; idx < 64 * 16; idx += 256) {
            int ar = idx >> 4;
            int cg = (idx & 15) * 4;
            int arow = rb + ar;
            float4 v = make_float4(0.f, 0.f, 0.f, 0.f);
            if (arow < N) {
                v = *(const float4*)(out1 + (size_t)arow * C1 + kc + cg);
                float4 sc = *(const float4*)(scale + kc + cg);
                float4 sh = *(const float4*)(shift + kc + cg);
                v.x = v.x * sc.x + sh.x;
                v.y = v.y * sc.y + sh.y;
                v.z = v.z * sc.z + sh.z;
                v.w = v.w * sc.w + sh.w;
                v.x = v.x > 0.f ? v.x : (__expf(v.x) - 1.f);
                v.y = v.y > 0.f ? v.y : (__expf(v.y) - 1.f);
                v.z = v.z > 0.f ? v.z : (__expf(v.z) - 1.f);
                v.w = v.w > 0.f ? v.w : (__expf(v.w) - 1.f);
            }
            *(float4*)&Asm[ar][cg] = v;
        }
        #pragma unroll
        for (int idx = t; idx < 64 * 40; idx += 256) {
            int k = idx / 40, j = idx - k * 40;
            Wsm[k * 48 + (j / 10) * 12 + (j % 10)] = W2[(size_t)(kc + k) * NC + j];
        }
        __syncthreads();
        #pragma unroll 4
        for (int k = 0; k < 64; ++k) {
            float a = Asm[r][k];
            const float* wp = &Wsm[k * 48 + jg * 12];
            float4 w0 = *(const float4*)(wp);
            float4 w1 = *(const float4*)(wp + 4);
            float2 wv = *(const float2*)(wp + 8);
            acc[0] += a * w0.x; acc[1] += a * w0.y;
            acc[2] += a * w0.z; acc[3] += a * w0.w;
            acc[4] += a * w1.x; acc[5] += a * w1.y;
            acc[6] += a * w1.z; acc[7] += a * w1.w;
            acc[8] += a * wv.x; acc[9] += a * wv.y;
        }
        __syncthreads();
    }

    float sp = 0.f, dp = 0.f;
    #pragma unroll
    for (int jj = 0; jj < 10; ++jj) {
        sp += acc[jj] * as2[j0 + jj];
        dp += acc[jj] * ad2[j0 + jj];
    }
    sp += __shfl_xor(sp, 1); sp += __shfl_xor(sp, 2);
    dp += __shfl_xor(dp, 1); dp += __shfl_xor(dp, 2);
    if (row < N) {
        if (jg == 0) { s2[row] = sp; d2[row] = dp; }
        #pragma unroll
        for (int jj = 0; jj < 10; jj += 2)
            *(float2*)(h2 + (size_t)row * NC + j0 + jj) =
                make_float2(acc[jj], acc[jj + 1]);
    }
}

// ---------------- layer-2 aggregate (v2) + bias + log_softmax --------------
__global__ __launch_bounds__(256)
void agg2_kernel(const float* __restrict__ h2, const float* __restrict__ s2,
                 const float* __restrict__ d2, const int* __restrict__ offs,
                 const int* __restrict__ ssrc, const float* __restrict__ b2,
                 float* __restrict__ out, int N)
{
    __shared__ float al[4][CAP2];
    __shared__ int   sr[4][CAP2];
    int w = threadIdx.x >> 6;
    int node = blockIdx.x * 4 + w;
    if (node >= N) return;
    int lane = threadIdx.x & 63;
    int beg = offs[node], end = offs[node + 1];
    int deg = end - beg;
    float dn = d2[node];

    float v;
    if (deg <= CAP2) {
        float mloc = -1e30f;
        for (int i = lane; i < deg; i += 64) {
            int s = ssrc[beg + i];
            sr[w][i] = s;
            float e = s2[s] + dn;
            e = e > 0.f ? e : 0.2f * e;
            al[w][i] = e;
            mloc = fmaxf(mloc, e);
        }
        #pragma unroll
        for (int off = 32; off; off >>= 1) mloc = fmaxf(mloc, __shfl_xor(mloc, off));
        float ssum = 0.f;
        for (int i = lane; i < deg; i += 64) {
            float ex = __expf(al[w][i] - mloc);
            al[w][i] = ex;
            ssum += ex;
        }
        #pragma unroll
        for (int off = 32; off; off >>= 1) ssum += __shfl_xor(ssum, off);
        float inv = 1.f / (ssum + 1e-16f);

        int j = lane < NC ? lane : 0;
        float acc0 = 0.f, acc1 = 0.f, acc2 = 0.f, acc3 = 0.f;
        int i = 0;
        for (; i + 4 <= deg; i += 4) {
            float a0 = al[w][i],     a1 = al[w][i + 1];
            float a2 = al[w][i + 2], a3 = al[w][i + 3];
            acc0 += h2[(size_t)sr[w][i]     * NC + j] * a0;
            acc1 += h2[(size_t)sr[w][i + 1] * NC + j] * a1;
            acc2 += h2[(size_t)sr[w][i + 2] * NC + j] * a2;
            acc3 += h2[(size_t)sr[w][i + 3] * NC + j] * a3;
        }
        for (; i < deg; ++i)
            acc0 += h2[(size_t)sr[w][i] * NC + j] * al[w][i];
        v = ((acc0 + acc1) + (acc2 + acc3)) * inv + b2[j];
    } else {
        float m = -1e30f, denom = 0.f;
        for (int p = beg; p < end; ++p) {
            float e = s2[ssrc[p]] + dn;
            e = e > 0.f ? e : 0.2f * e;
            float mn = fmaxf(m, e);
            denom = denom * __expf(m - mn) + __expf(e - mn);
            m = mn;
        }
        float inv = 1.f / (denom + 1e-16f);
        int j = lane < NC ? lane : 0;
        float acc = 0.f;
        for (int p = beg; p < end; ++p) {
            int s = ssrc[p];
            float e = s2[s] + dn;
            e = e > 0.f ? e : 0.2f * e;
            acc += h2[(size_t)s * NC + j] * (__expf(e - m) * inv);
        }
        v = acc + b2[j];
    }

    float vm = lane < NC ? v : -1e30f;
    #pragma unroll
    for (int off = 32; off > 0; off >>= 1) vm = fmaxf(vm, __shfl_xor(vm, off));
    float ex = lane < NC ? __expf(v - vm) : 0.f;
    #pragma unroll
    for (int off = 32; off > 0; off >>= 1) ex += __shfl_xor(ex, off);
    if (lane < NC) out[(size_t)node * NC + lane] = v - vm - __logf(ex);
}

// ---------------- host ----------------------------------------------------
extern "C" void kernel_launch(void* const* d_in, const int* in_sizes, int n_in,
                              void* d_out, int out_size, void* d_ws, size_t ws_size,
                              hipStream_t stream)
{
    const float* x   = (const float*)d_in[0];
    const int*   ei  = (const int*)d_in[1];
    const float* W1  = (const float*)d_in[2];
    const float* as1 = (const float*)d_in[3];
    const float* ad1 = (const float*)d_in[4];
    const float* b1  = (const float*)d_in[5];
    const float* gm  = (const float*)d_in[6];
    const float* bt  = (const float*)d_in[7];
    const float* W2  = (const float*)d_in[8];
    const float* as2 = (const float*)d_in[9];
    const float* ad2 = (const float*)d_in[10];
    const float* b2  = (const float*)d_in[11];
    const int N = in_sizes[0] / FIN;
    const int E = in_sizes[1] / 2;
    const int NPAD = (N + 63) & ~63;

    char* p = (char*)d_ws;
    auto take = [&](size_t bytes) {
        char* r = p; p += (bytes + 255) & ~(size_t)255; return r;
    };
    __half* Hm       = (__half*)take((size_t)N * C1 * 2);
    _Float16* Xh     = (_Float16*)take((size_t)NPAD * FIN * 2);
    _Float16* W1t    = (_Float16*)take((size_t)FIN * C1 * 2);
    float* out1   = (float*)take((size_t)N * C1 * 4);
    float* h2     = (float*)take((size_t)N * NC * 4);
    float* s1     = (float*)take((size_t)N * H1N * 4);
    float* d1     = (float*)take((size_t)N * H1N * 4);
    float* s2     = (float*)take((size_t)N * 4);
    float* d2v    = (float*)take((size_t)N * 4);
    float* colsum = (float*)take(C1 * 4);
    float* colsq  = (float*)take(C1 * 4);
    float* bnsc   = (float*)take(C1 * 4);
    float* bnsh   = (float*)take(C1 * 4);
    int*   counts = (int*)take((size_t)N * 4);
    int*   offs   = (int*)take((size_t)(N + 1) * 4);
    int*   fill   = (int*)take((size_t)N * 4);
    int*   ssrc   = (int*)take((size_t)(E + N) * 4);
    int*   eflag  = (int*)take(256);

    detect_kernel<<<1, 64, 0, stream>>>(ei, eflag, E);
    init_kernel<<<(N + 255) / 256, 256, 0, stream>>>(counts, fill, colsum, colsq, N);
    xcast_kernel<<<(NPAD * FIN / 4 + 255) / 256, 256, 0, stream>>>(x, Xh, N, NPAD);
    w1cast_kernel<<<16, 256, 0, stream>>>(W1, W1t);
    gemm1_mfma_kernel<<<NPAD / 64, 256, 0, stream>>>(Xh, W1t, as1, ad1, Hm, s1, d1, N);
    hist_kernel<<<(E + 255) / 256, 256, 0, stream>>>(ei, eflag, counts, E);
    scan_kernel<<<1, 1024, 0, stream>>>(counts, offs, N);
    scatter_kernel<<<(E + N + 255) / 256, 256, 0, stream>>>(ei, eflag, offs, fill, ssrc, E, N);
    agg1_kernel<<<N, 256, 0, stream>>>(Hm, s1, d1, offs, ssrc, b1, out1, N);
    bnstats_kernel<<<1024, 256, 0, stream>>>(out1, colsum, colsq, N);
    bnfin_kernel<<<1, 256, 0, stream>>>(colsum, colsq, gm, bt, bnsc, bnsh, N);
    gemm2_kernel<<<(N + 63) / 64, 256, 0, stream>>>(out1, bnsc, bnsh, W2, as2, ad2, h2, s2, d2v, N);
    agg2_kernel<<<(N + 3) / 4, 256, 0, stream>>>(h2, s2, d2v, offs, ssrc, b2, (float*)d_out, N);
}

// Round 14
// 466.089 us; speedup vs baseline: 1.5651x; 1.0192x over previous
//
#include <hip/hip_runtime.h>
#include <hip/hip_fp16.h>

constexpr int FIN = 256;   // input features
constexpr int C1  = 256;   // H1*hidden (layer-1 concat width)
constexpr int HID = 64;
constexpr int H1N = 4;
constexpr int NC  = 40;    // classes
constexpr int CAP2 = 128;  // agg2 per-wave LDS capacity

using f16x8 = __attribute__((ext_vector_type(8))) _Float16;
using f32x4 = __attribute__((ext_vector_type(4))) float;

// ---------------- edge dtype detect: int32 vs int64 -----------------------
__global__ __launch_bounds__(64)
void detect_kernel(const int* __restrict__ ei, int* __restrict__ flag, int E)
{
    int lane = threadIdx.x;
    int q = lane * (E / 64);
    int v = ei[2 * q + 1];
    unsigned long long nz = __ballot(v != 0);
    if (lane == 0) flag[0] = (nz == 0ull) ? 2 : 1;
}

// ---------------- init ----------------------------------------------------
__global__ __launch_bounds__(256)
void init_kernel(int* __restrict__ counts, int* __restrict__ fill,
                 float* __restrict__ colsum, float* __restrict__ colsq, int N)
{
    int t = blockIdx.x * 256 + threadIdx.x;
    if (t < N) { counts[t] = 1; fill[t] = 0; }
    if (t < C1) { colsum[t] = 0.f; colsq[t] = 0.f; }
}

// ---------------- X -> fp16 (rows >= N zero-padded) ------------------------
__global__ __launch_bounds__(256)
void xcast_kernel(const float* __restrict__ X, _Float16* __restrict__ Xh,
                  int N, int NPAD)
{
    int idx = (blockIdx.x * 256 + threadIdx.x) * 4;
    if (idx >= NPAD * FIN) return;
    int row = idx >> 8;
    _Float16 h4[4];
    if (row < N) {
        float4 v = *(const float4*)(X + idx);
        h4[0] = (_Float16)v.x; h4[1] = (_Float16)v.y;
        h4[2] = (_Float16)v.z; h4[3] = (_Float16)v.w;
    } else {
        h4[0] = h4[1] = h4[2] = h4[3] = (_Float16)0.f;
    }
    *(uint2*)(Xh + idx) = *(uint2*)h4;
}

// ---------------- W1 -> fp16 transposed [col][k] ---------------------------
__global__ __launch_bounds__(256)
void w1cast_kernel(const float* __restrict__ W1, _Float16* __restrict__ W1t)
{
    __shared__ float tile[64][65];
    int bx = blockIdx.x & 3, by = blockIdx.x >> 2;
    int t = threadIdx.x;
    int c = t & 63, r4 = (t >> 6) * 16;
    #pragma unroll
    for (int i = 0; i < 16; ++i)
        tile[r4 + i][c] = W1[(size_t)(by * 64 + r4 + i) * C1 + bx * 64 + c];
    __syncthreads();
    #pragma unroll
    for (int i = 0; i < 16; ++i)
        W1t[(size_t)(bx * 64 + r4 + i) * FIN + by * 64 + c] =
            (_Float16)tile[c][r4 + i];
}

// ---------------- GEMM1 via fp16 MFMA, fused s1/d1 -------------------------
__global__ __launch_bounds__(256)
void gemm1_mfma_kernel(const _Float16* __restrict__ Xh,
                       const _Float16* __restrict__ W1t,
                       const float* __restrict__ as1, const float* __restrict__ ad1,
                       __half* __restrict__ Hm, float* __restrict__ s1,
                       float* __restrict__ d1, int N)
{
    const int t    = threadIdx.x;
    const int lane = t & 63;
    const int w    = t >> 6;
    const int rowbase = blockIdx.x * 64 + w * 16;
    const int lrow = lane & 15;
    const int kgrp = lane >> 4;
    const int arow = rowbase + lrow;          // A-load row (Xh is padded)

    f32x4 acc[16];
    #pragma unroll
    for (int i = 0; i < 16; ++i) acc[i] = f32x4{0.f, 0.f, 0.f, 0.f};

    #pragma unroll
    for (int ks = 0; ks < 8; ++ks) {
        f16x8 a = *(const f16x8*)(Xh + (size_t)arow * FIN + ks * 32 + kgrp * 8);
        #pragma unroll
        for (int ct = 0; ct < 16; ++ct) {
            f16x8 b = *(const f16x8*)(W1t + (size_t)(ct * 16 + lrow) * FIN
                                      + ks * 32 + kgrp * 8);
            acc[ct] = __builtin_amdgcn_mfma_f32_16x16x32_f16(a, b, acc[ct], 0, 0, 0);
        }
    }

    // epilogue: lane holds rows rowbase + kgrp*4 + reg, cols ct*16 + lrow
    #pragma unroll
    for (int reg = 0; reg < 4; ++reg) {
        int r = rowbase + kgrp * 4 + reg;
        bool ok = r < N;
        #pragma unroll
        for (int h = 0; h < 4; ++h) {
            float sp = 0.f, dp = 0.f;
            #pragma unroll
            for (int q = 0; q < 4; ++q) {
                int ct = h * 4 + q;
                float v = acc[ct][reg];
                sp += v * as1[ct * 16 + lrow];
                dp += v * ad1[ct * 16 + lrow];
            }
            sp += __shfl_xor(sp, 1); sp += __shfl_xor(sp, 2);
            sp += __shfl_xor(sp, 4); sp += __shfl_xor(sp, 8);
            dp += __shfl_xor(dp, 1); dp += __shfl_xor(dp, 2);
            dp += __shfl_xor(dp, 4); dp += __shfl_xor(dp, 8);
            if (ok && lrow == 0) {
                s1[r * H1N + h] = sp;
                d1[r * H1N + h] = dp;
            }
        }
        if (ok) {
            #pragma unroll
            for (int ct = 0; ct < 16; ++ct)
                Hm[(size_t)r * C1 + ct * 16 + lrow] = __float2half(acc[ct][reg]);
        }
    }
}

// ---------------- CSR build ----------------------------------------------
__global__ __launch_bounds__(256)
void hist_kernel(const int* __restrict__ ei, const int* __restrict__ flag,
                 int* __restrict__ counts, int E)
{
    int t = blockIdx.x * 256 + threadIdx.x;
    int stride = flag[0];
    if (t < E) atomicAdd(&counts[ei[(size_t)stride * (E + t)]], 1);
}

__global__ __launch_bounds__(1024)
void scan_kernel(const int* __restrict__ cnt, int* __restrict__ offs, int N)
{
    __shared__ int wsum[16];
    __shared__ int carry_s;
    const int t = threadIdx.x, lane = t & 63, w = t >> 6;
    if (t == 0) carry_s = 0;
    __syncthreads();
    for (int base = 0; base < N; base += 1024) {
        int idx = base + t;
        int v = (idx < N) ? cnt[idx] : 0;
        int incl = v;
        #pragma unroll
        for (int off = 1; off < 64; off <<= 1) {
            int u = __shfl_up(incl, off);
            if (lane >= off) incl += u;
        }
        if (lane == 63) wsum[w] = incl;
        __syncthreads();
        int wpre = 0;
        for (int i = 0; i < w; ++i) wpre += wsum[i];
        int c = carry_s;
        if (idx < N) offs[idx] = c + wpre + incl - v;
        __syncthreads();
        if (t == 1023) carry_s = c + wpre + incl;
        __syncthreads();
    }
    if (t == 0) offs[N] = carry_s;
}

__global__ __launch_bounds__(256)
void scatter_kernel(const int* __restrict__ ei, const int* __restrict__ flag,
                    const int* __restrict__ offs, int* __restrict__ fill,
                    int* __restrict__ ssrc, int E, int N)
{
    int t = blockIdx.x * 256 + threadIdx.x;
    if (t >= E + N) return;
    int stride = flag[0];
    int s, d;
    if (t < E) {
        s = ei[(size_t)stride * t];
        d = ei[(size_t)stride * (E + t)];
    } else {
        s = t - E; d = s;
    }
    int pos = offs[d] + atomicAdd(&fill[d], 1);
    ssrc[pos] = s;
}

// ---------------- alpha stats: normalized per-(edge,head) attention -------
// Wave per node (4 nodes/block), no LDS/barriers. Lane = (edge-slot ig,
// head h): ig = lane>>2 (16 slots), h = lane&3. Per-head segment max/sum
// via shfl_xor over offsets 4..32 (reduces slots, keeps heads separate).
// Writes alphaE[p*4+h] = exp(e-m)/denom -- 256B-coalesced per round.
__global__ __launch_bounds__(256)
void astats_kernel(const float* __restrict__ s1, const float* __restrict__ d1,
                   const int* __restrict__ offs, const int* __restrict__ ssrc,
                   float* __restrict__ alphaE, int N)
{
    int w = threadIdx.x >> 6;
    int n = blockIdx.x * 4 + w;
    if (n >= N) return;
    int lane = threadIdx.x & 63;
    int h  = lane & 3;
    int ig = lane >> 2;
    int beg = offs[n], end = offs[n + 1];
    float dh = d1[n * H1N + h];

    float m = -1e30f;
    for (int p = beg + ig; p < end; p += 16) {
        float e = s1[ssrc[p] * H1N + h] + dh;
        e = e > 0.f ? e : 0.2f * e;          // leaky_relu 0.2
        m = fmaxf(m, e);
    }
    m = fmaxf(m, __shfl_xor(m, 4));
    m = fmaxf(m, __shfl_xor(m, 8));
    m = fmaxf(m, __shfl_xor(m, 16));
    m = fmaxf(m, __shfl_xor(m, 32));

    float ssum = 0.f;
    for (int p = beg + ig; p < end; p += 16) {
        float e = s1[ssrc[p] * H1N + h] + dh;
        e = e > 0.f ? e : 0.2f * e;
        ssum += __expf(e - m);
    }
    ssum += __shfl_xor(ssum, 4);
    ssum += __shfl_xor(ssum, 8);
    ssum += __shfl_xor(ssum, 16);
    ssum += __shfl_xor(ssum, 32);
    float inv = 1.f / (ssum + 1e-16f);

    for (int p = beg + ig; p < end; p += 16) {
        float e = s1[ssrc[p] * H1N + h] + dh;
        e = e > 0.f ? e : 0.2f * e;
        alphaE[(size_t)p * H1N + h] = __expf(e - m) * inv;
    }
}

// ---------------- layer-1 aggregate (v5): pure gather ----------------------
// 2 nodes/block, 128 threads/node, thread = half2 channel pair. No LDS,
// no barriers, no deg cap; 4 edge-loads in flight per thread.
__global__ __launch_bounds__(256)
void agg1_kernel(const __half* __restrict__ Hm, const float* __restrict__ alphaE,
                 const int* __restrict__ offs, const int* __restrict__ ssrc,
                 const float* __restrict__ b1, float* __restrict__ out1, int N)
{
    const int n = blockIdx.x * 2 + (threadIdx.x >> 7);
    if (n >= N) return;
    const int l = threadIdx.x & 127;
    const int c = 2 * l;               // channel pair
    const int h = l >> 5;              // head of this pair
    const int beg = offs[n], end = offs[n + 1];

    float ax = 0.f, ay = 0.f, bx = 0.f, by = 0.f;
    float cx = 0.f, cy = 0.f, dx = 0.f, dy = 0.f;
    int p = beg;
    for (; p + 4 <= end; p += 4) {
        int s0 = ssrc[p],     s1i = ssrc[p + 1];
        int s2 = ssrc[p + 2], s3  = ssrc[p + 3];
        float a0 = alphaE[(size_t)(p)     * H1N + h];
        float a1 = alphaE[(size_t)(p + 1) * H1N + h];
        float a2 = alphaE[(size_t)(p + 2) * H1N + h];
        float a3 = alphaE[(size_t)(p + 3) * H1N + h];
        float2 v0 = __half22float2(*(const __half2*)(Hm + (size_t)s0  * C1 + c));
        float2 v1 = __half22float2(*(const __half2*)(Hm + (size_t)s1i * C1 + c));
        float2 v2 = __half22float2(*(const __half2*)(Hm + (size_t)s2  * C1 + c));
        float2 v3 = __half22float2(*(const __half2*)(Hm + (size_t)s3  * C1 + c));
        ax += v0.x * a0; ay += v0.y * a0;
        bx += v1.x * a1; by += v1.y * a1;
        cx += v2.x * a2; cy += v2.y * a2;
        dx += v3.x * a3; dy += v3.y * a3;
    }
    for (; p < end; ++p) {
        int s0 = ssrc[p];
        float a0 = alphaE[(size_t)p * H1N + h];
        float2 v0 = __half22float2(*(const __half2*)(Hm + (size_t)s0 * C1 + c));
        ax += v0.x * a0; ay += v0.y * a0;
    }
    float sx = (ax + bx) + (cx + dx);
    float sy = (ay + by) + (cy + dy);
    float2 r;
    r.x = sx + b1[c];
    r.y = sy + b1[c + 1];
    *(float2*)(out1 + (size_t)n * C1 + c) = r;
}

// ---------------- BN column stats (1024 blocks: 4/CU) ----------------------
__global__ __launch_bounds__(256)
void bnstats_kernel(const float* __restrict__ out1, float* __restrict__ colsum,
                    float* __restrict__ colsq, int N)
{
    int t = threadIdx.x;
    float s = 0.f, q = 0.f;
    for (int r = blockIdx.x; r < N; r += gridDim.x) {
        float v = out1[(size_t)r * C1 + t];
        s += v; q += v * v;
    }
    atomicAdd(&colsum[t], s);
    atomicAdd(&colsq[t], q);
}

__global__ __launch_bounds__(256)
void bnfin_kernel(const float* __restrict__ colsum, const float* __restrict__ colsq,
                  const float* __restrict__ gamma, const float* __restrict__ beta,
                  float* __restrict__ scale, float* __restrict__ shift, int N)
{
    int t = threadIdx.x;
    float mu  = colsum[t] / (float)N;
    float var = colsq[t] / (float)N - mu * mu;
    float sc  = gamma[t] * rsqrtf(var + 1e-5f);
    scale[t] = sc;
    shift[t] = beta[t] - mu * sc;
}

// ---------------- GEMM2 (v2): 64 rows/block, thread=(row, jg:10 cols) -----
__global__ __launch_bounds__(256)
void gemm2_kernel(const float* __restrict__ out1, const float* __restrict__ scale,
                  const float* __restrict__ shift, const float* __restrict__ W2,
                  const float* __restrict__ as2, const float* __restrict__ ad2,
                  float* __restrict__ h2, float* __restrict__ s2,
                  float* __restrict__ d2, int N)
{
    __shared__ float Asm[64][68];
    __shared__ float Wsm[64 * 48];
    const int t   = threadIdx.x;
    const int r   = t >> 2;
    const int jg  = t & 3;
    const int rb  = blockIdx.x * 64;
    const int row = rb + r;
    const int j0  = jg * 10;

    float acc[10] = {};

    for (int kc = 0; kc < C1; kc += 64) {
        #pragma unroll
        for (int idx = t; idx < 64 * 16; idx += 256) {
            int ar = idx >> 4;
            int cg = (idx & 15) * 4;
            int arow = rb + ar;
            float4 v = make_float4(0.f, 0.f, 0.f, 0.f);
            if (arow < N) {
                v = *(const float4*)(out1 + (size_t)arow * C1 + kc + cg);
                float4 sc = *(const float4*)(scale + kc + cg);
                float4 sh = *(const float4*)(shift + kc + cg);
                v.x = v.x * sc.x + sh.x;
                v.y = v.y * sc.y + sh.y;
                v.z = v.z * sc.z + sh.z;
                v.w = v.w * sc.w + sh.w;
                v.x = v.x > 0.f ? v.x : (__expf(v.x) - 1.f);
                v.y = v.y > 0.f ? v.y : (__expf(v.y) - 1.f);
                v.z = v.z > 0.f ? v.z : (__expf(v.z) - 1.f);
                v.w = v.w > 0.f ? v.w : (__expf(v.w) - 1.f);
            }
            *(float4*)&Asm[ar][cg] = v;
        }
        #pragma unroll
        for (int idx = t; idx < 64 * 40; idx += 256) {
            int k = idx / 40, j = idx - k * 40;
            Wsm[k * 48 + (j / 10) * 12 + (j % 10)] = W2[(size_t)(kc + k) * NC + j];
        }
        __syncthreads();
        #pragma unroll 4
        for (int k = 0; k < 64; ++k) {
            float a = Asm[r][k];
            const float* wp = &Wsm[k * 48 + jg * 12];
            float4 w0 = *(const float4*)(wp);
            float4 w1 = *(const float4*)(wp + 4);
            float2 wv = *(const float2*)(wp + 8);
            acc[0] += a * w0.x; acc[1] += a * w0.y;
            acc[2] += a * w0.z; acc[3] += a * w0.w;
            acc[4] += a * w1.x; acc[5] += a * w1.y;
            acc[6] += a * w1.z; acc[7] += a * w1.w;
            acc[8] += a * wv.x; acc[9] += a * wv.y;
        }
        __syncthreads();
    }

    float sp = 0.f, dp = 0.f;
    #pragma unroll
    for (int jj = 0; jj < 10; ++jj) {
        sp += acc[jj] * as2[j0 + jj];
        dp += acc[jj] * ad2[j0 + jj];
    }
    sp += __shfl_xor(sp, 1); sp += __shfl_xor(sp, 2);
    dp += __shfl_xor(dp, 1); dp += __shfl_xor(dp, 2);
    if (row < N) {
        if (jg == 0) { s2[row] = sp; d2[row] = dp; }
        #pragma unroll
        for (int jj = 0; jj < 10; jj += 2)
            *(float2*)(h2 + (size_t)row * NC + j0 + jj) =
                make_float2(acc[jj], acc[jj + 1]);
    }
}

// ---------------- layer-2 aggregate (v2) + bias + log_softmax --------------
__global__ __launch_bounds__(256)
void agg2_kernel(const float* __restrict__ h2, const float* __restrict__ s2,
                 const float* __restrict__ d2, const int* __restrict__ offs,
                 const int* __restrict__ ssrc, const float* __restrict__ b2,
                 float* __restrict__ out, int N)
{
    __shared__ float al[4][CAP2];
    __shared__ int   sr[4][CAP2];
    int w = threadIdx.x >> 6;
    int node = blockIdx.x * 4 + w;
    if (node >= N) return;
    int lane = threadIdx.x & 63;
    int beg = offs[node], end = offs[node + 1];
    int deg = end - beg;
    float dn = d2[node];

    float v;
    if (deg <= CAP2) {
        float mloc = -1e30f;
        for (int i = lane; i < deg; i += 64) {
            int s = ssrc[beg + i];
            sr[w][i] = s;
            float e = s2[s] + dn;
            e = e > 0.f ? e : 0.2f * e;
            al[w][i] = e;
            mloc = fmaxf(mloc, e);
        }
        #pragma unroll
        for (int off = 32; off; off >>= 1) mloc = fmaxf(mloc, __shfl_xor(mloc, off));
        float ssum = 0.f;
        for (int i = lane; i < deg; i += 64) {
            float ex = __expf(al[w][i] - mloc);
            al[w][i] = ex;
            ssum += ex;
        }
        #pragma unroll
        for (int off = 32; off; off >>= 1) ssum += __shfl_xor(ssum, off);
        float inv = 1.f / (ssum + 1e-16f);

        int j = lane < NC ? lane : 0;
        float acc0 = 0.f, acc1 = 0.f, acc2 = 0.f, acc3 = 0.f;
        int i = 0;
        for (; i + 4 <= deg; i += 4) {
            float a0 = al[w][i],     a1 = al[w][i + 1];
            float a2 = al[w][i + 2], a3 = al[w][i + 3];
            acc0 += h2[(size_t)sr[w][i]     * NC + j] * a0;
            acc1 += h2[(size_t)sr[w][i + 1] * NC + j] * a1;
            acc2 += h2[(size_t)sr[w][i + 2] * NC + j] * a2;
            acc3 += h2[(size_t)sr[w][i + 3] * NC + j] * a3;
        }
        for (; i < deg; ++i)
            acc0 += h2[(size_t)sr[w][i] * NC + j] * al[w][i];
        v = ((acc0 + acc1) + (acc2 + acc3)) * inv + b2[j];
    } else {
        float m = -1e30f, denom = 0.f;
        for (int p = beg; p < end; ++p) {
            float e = s2[ssrc[p]] + dn;
            e = e > 0.f ? e : 0.2f * e;
            float mn = fmaxf(m, e);
            denom = denom * __expf(m - mn) + __expf(e - mn);
            m = mn;
        }
        float inv = 1.f / (denom + 1e-16f);
        int j = lane < NC ? lane : 0;
        float acc = 0.f;
        for (int p = beg; p < end; ++p) {
            int s = ssrc[p];
            float e = s2[s] + dn;
            e = e > 0.f ? e : 0.2f * e;
            acc += h2[(size_t)s * NC + j] * (__expf(e - m) * inv);
        }
        v = acc + b2[j];
    }

    float vm = lane < NC ? v : -1e30f;
    #pragma unroll
    for (int off = 32; off > 0; off >>= 1) vm = fmaxf(vm, __shfl_xor(vm, off));
    float ex = lane < NC ? __expf(v - vm) : 0.f;
    #pragma unroll
    for (int off = 32; off > 0; off >>= 1) ex += __shfl_xor(ex, off);
    if (lane < NC) out[(size_t)node * NC + lane] = v - vm - __logf(ex);
}

// ---------------- host ----------------------------------------------------
extern "C" void kernel_launch(void* const* d_in, const int* in_sizes, int n_in,
                              void* d_out, int out_size, void* d_ws, size_t ws_size,
                              hipStream_t stream)
{
    const float* x   = (const float*)d_in[0];
    const int*   ei  = (const int*)d_in[1];
    const float* W1  = (const float*)d_in[2];
    const float* as1 = (const float*)d_in[3];
    const float* ad1 = (const float*)d_in[4];
    const float* b1  = (const float*)d_in[5];
    const float* gm  = (const float*)d_in[6];
    const float* bt  = (const float*)d_in[7];
    const float* W2  = (const float*)d_in[8];
    const float* as2 = (const float*)d_in[9];
    const float* ad2 = (const float*)d_in[10];
    const float* b2  = (const float*)d_in[11];
    const int N = in_sizes[0] / FIN;
    const int E = in_sizes[1] / 2;
    const int NPAD = (N + 63) & ~63;

    char* p = (char*)d_ws;
    auto take = [&](size_t bytes) {
        char* r = p; p += (bytes + 255) & ~(size_t)255; return r;
    };
    __half* Hm       = (__half*)take((size_t)N * C1 * 2);
    _Float16* Xh     = (_Float16*)take((size_t)NPAD * FIN * 2);
    _Float16* W1t    = (_Float16*)take((size_t)FIN * C1 * 2);
    float* alphaE = (float*)take((size_t)(E + N) * H1N * 4);
    float* out1   = (float*)take((size_t)N * C1 * 4);
    float* h2     = (float*)take((size_t)N * NC * 4);
    float* s1     = (float*)take((size_t)N * H1N * 4);
    float* d1     = (float*)take((size_t)N * H1N * 4);
    float* s2     = (float*)take((size_t)N * 4);
    float* d2v    = (float*)take((size_t)N * 4);
    float* colsum = (float*)take(C1 * 4);
    float* colsq  = (float*)take(C1 * 4);
    float* bnsc   = (float*)take(C1 * 4);
    float* bnsh   = (float*)take(C1 * 4);
    int*   counts = (int*)take((size_t)N * 4);
    int*   offs   = (int*)take((size_t)(N + 1) * 4);
    int*   fill   = (int*)take((size_t)N * 4);
    int*   ssrc   = (int*)take((size_t)(E + N) * 4);
    int*   eflag  = (int*)take(256);

    detect_kernel<<<1, 64, 0, stream>>>(ei, eflag, E);
    init_kernel<<<(N + 255) / 256, 256, 0, stream>>>(counts, fill, colsum, colsq, N);
    xcast_kernel<<<(NPAD * FIN / 4 + 255) / 256, 256, 0, stream>>>(x, Xh, N, NPAD);
    w1cast_kernel<<<16, 256, 0, stream>>>(W1, W1t);
    gemm1_mfma_kernel<<<NPAD / 64, 256, 0, stream>>>(Xh, W1t, as1, ad1, Hm, s1, d1, N);
    hist_kernel<<<(E + 255) / 256, 256, 0, stream>>>(ei, eflag, counts, E);
    scan_kernel<<<1, 1024, 0, stream>>>(counts, offs, N);
    scatter_kernel<<<(E + N + 255) / 256, 256, 0, stream>>>(ei, eflag, offs, fill, ssrc, E, N);
    astats_kernel<<<(N + 3) / 4, 256, 0, stream>>>(s1, d1, offs, ssrc, alphaE, N);
    agg1_kernel<<<(N + 1) / 2, 256, 0, stream>>>(Hm, alphaE, offs, ssrc, b1, out1, N);
    bnstats_kernel<<<1024, 256, 0, stream>>>(out1, colsum, colsq, N);
    bnfin_kernel<<<1, 256, 0, stream>>>(colsum, colsq, gm, bt, bnsc, bnsh, N);
    gemm2_kernel<<<(N + 63) / 64, 256, 0, stream>>>(out1, bnsc, bnsh, W2, as2, ad2, h2, s2, d2v, N);
    agg2_kernel<<<(N + 3) / 4, 256, 0, stream>>>(h2, s2, d2v, offs, ssrc, b2, (float*)d_out, N);
}